// Round 1
// baseline (456.430 us; speedup 1.0000x reference)
//
#include <hip/hip_runtime.h>
#include <hip/hip_bf16.h>
#include <math.h>

// Sizes
#define HH 4
#define BB 8
#define CC 64
#define RR 64
#define LL 2048
#define AA 8
#define HC 256   // H*C
#define EPS 1e-5f

// ---------------------------------------------------------------------------
// Kernel A: K = key_w[h] @ inputs[h,b]  (R x L), V = value_w[h] @ inputs[h,b]
// grid (H*B, L/256), block 256
__global__ __launch_bounds__(256) void kA(const float* __restrict__ inp,
                                          const float* __restrict__ kw,
                                          const float* __restrict__ vw,
                                          float* __restrict__ K,
                                          float* __restrict__ V) {
    int hb = blockIdx.x;
    int h = hb >> 3;
    int l0 = blockIdx.y * 256;
    __shared__ float in_s[64][256];
    const float* ibase = inp + (size_t)(hb * 64) * LL + l0;
    int t = threadIdx.x;
    for (int c = 0; c < 64; ++c) in_s[c][t] = ibase[c * LL + t];
    __syncthreads();
    const float* kwh = kw + h * 64 * 64;
    const float* vwh = vw + h * 64 * 64;
    float* Kb = K + (size_t)(hb * 64) * LL + l0;
    float* Vb = V + (size_t)(hb * 64) * LL + l0;
    for (int rb = 0; rb < 8; ++rb) {
        float accK[8], accV[8];
#pragma unroll
        for (int i = 0; i < 8; ++i) { accK[i] = 0.f; accV[i] = 0.f; }
        for (int c = 0; c < 64; ++c) {
            float x = in_s[c][t];
#pragma unroll
            for (int i = 0; i < 8; ++i) {
                accK[i] += kwh[(rb * 8 + i) * 64 + c] * x;
                accV[i] += vwh[(rb * 8 + i) * 64 + c] * x;
            }
        }
#pragma unroll
        for (int i = 0; i < 8; ++i) {
            Kb[(size_t)(rb * 8 + i) * LL + t] = accK[i];
            Vb[(size_t)(rb * 8 + i) * LL + t] = accV[i];
        }
    }
}

// ---------------------------------------------------------------------------
// Kernel B: banded softmax stats per (h,b,l): u and w[5]
// grid (H*B, L/128), block 128
__global__ __launch_bounds__(128) void kB(const float* __restrict__ K,
                                          const float* __restrict__ hidden,
                                          float* __restrict__ U,
                                          float* __restrict__ W) {
    int hb = blockIdx.x;
    int b = hb & 7;
    int l0 = blockIdx.y * 128;
    __shared__ float k_s[64][132];
    __shared__ float h_s[64][128];
    const float* Kb = K + (size_t)(hb * 64) * LL;
    int t = threadIdx.x;
    for (int idx = t; idx < 64 * 132; idx += 128) {
        int r = idx / 132, j = idx % 132;
        int m = l0 - 2 + j;
        k_s[r][j] = (m >= 0 && m < LL) ? Kb[(size_t)r * LL + m] : 0.f;
    }
    const float* hbp = hidden + (size_t)(b * 64) * LL + l0;
    for (int r = 0; r < 64; ++r) h_s[r][t] = hbp[(size_t)r * LL + t];
    __syncthreads();
    int l = l0 + t;
    float raw[5];
    float mx = 0.f;
    int nv = 0;
#pragma unroll
    for (int d = 0; d < 5; ++d) {
        int m = l + d - 2;
        bool valid = (m >= 0 && m < LL);
        float acc = 0.f;
        if (valid) {
            for (int r = 0; r < 64; ++r) acc += h_s[r][t] * k_s[r][t + d];
            acc *= 0.125f;   // q scale 1/sqrt(64)
            nv++;
            mx = fmaxf(mx, acc);
        }
        raw[d] = valid ? acc : -1e30f;
    }
    float e0 = __expf(-mx);
    float Z = (float)(LL - nv) * e0;
    float w[5];
#pragma unroll
    for (int d = 0; d < 5; ++d) {
        float e = (raw[d] > -1e29f) ? __expf(raw[d] - mx) : 0.f;
        w[d] = e;
        Z += e;
    }
    float inv = 1.f / Z;
    U[(size_t)hb * LL + l] = e0 * inv;
#pragma unroll
    for (int d = 0; d < 5; ++d) W[((size_t)hb * LL + l) * 5 + d] = w[d] * inv;
}

// ---------------------------------------------------------------------------
// Kernel C: S[hb][c] = sum_l V[hb][c][l] * U[hb][l]
// grid (H*B), block 256
__global__ __launch_bounds__(256) void kC(const float* __restrict__ V,
                                          const float* __restrict__ U,
                                          float* __restrict__ S) {
    int hb = blockIdx.x;
    int t = threadIdx.x;
    int c = t >> 2, sub = t & 3;
    const float* Vb = V + (size_t)(hb * 64 + c) * LL;
    const float* Ub = U + (size_t)hb * LL;
    float acc = 0.f;
    for (int l = sub; l < LL; l += 4) acc += Vb[l] * Ub[l];
    __shared__ float red[256];
    red[t] = acc;
    __syncthreads();
    if (sub == 0) S[hb * 64 + c] = red[t] + red[t + 1] + red[t + 2] + red[t + 3];
}

// ---------------------------------------------------------------------------
// Kernel D: val + residual -> x; channel attention -> gate; write XG
// grid (B, L/64), block 256
__global__ __launch_bounds__(256) void kD(const float* __restrict__ inp,
                                          const float* __restrict__ hidden,
                                          const float* __restrict__ V,
                                          const float* __restrict__ U,
                                          const float* __restrict__ W,
                                          const float* __restrict__ S,
                                          const float* __restrict__ w1,
                                          const float* __restrict__ b1,
                                          const float* __restrict__ w2,
                                          const float* __restrict__ b2,
                                          float* __restrict__ XG) {
    int b = blockIdx.x;
    int m0 = blockIdx.y * 64;
    __shared__ float x_s[256][64];
    __shared__ float hid_s[64][64];
    __shared__ float u_s[4][68];
    __shared__ float w_s[4][68][5];
    __shared__ float a_s[8][64];
    __shared__ float S_s[256];
    int t = threadIdx.x;
    int m = t & 63;
    int wv = t >> 6;  // wave id 0..3
    // stage hidden tile
    for (int i = 0; i < 16; ++i) {
        int r = wv * 16 + i;
        hid_s[r][m] = hidden[(size_t)(b * 64 + r) * LL + m0 + m];
    }
    // stage u, w (range [m0-2, m0+66))
    for (int idx = t; idx < 4 * 68; idx += 256) {
        int h = idx / 68, j = idx % 68;
        int l = m0 - 2 + j;
        bool v = (l >= 0 && l < LL);
        int hb = h * 8 + b;
        u_s[h][j] = v ? U[(size_t)hb * LL + l] : 0.f;
#pragma unroll
        for (int d = 0; d < 5; ++d)
            w_s[h][j][d] = v ? W[((size_t)hb * LL + l) * 5 + d] : 0.f;
    }
    // stage S
    S_s[t] = S[((t >> 6) * 8 + b) * 64 + (t & 63)];
    __syncthreads();
    // phase 1: x[ch][m] = inputs + S + banded correction
    {
        int h = wv;  // wave handles one head's 64 channels
        int hb = h * 8 + b;
        for (int c = 0; c < 64; ++c) {
            int ch = h * 64 + c;
            float val = S_s[ch];
#pragma unroll
            for (int o = -2; o <= 2; ++o) {
                int l = m0 + m - o;
                if (l >= 0 && l < LL) {
                    int j = l - (m0 - 2);
                    val += V[(size_t)(hb * 64 + c) * LL + l] * (w_s[h][j][o + 2] - u_s[h][j]);
                }
            }
            x_s[ch][m] = inp[(size_t)(hb * 64 + c) * LL + m0 + m] + val;
        }
    }
    __syncthreads();
    // phase 2: a[o][m] = relu(ca_w1 . cat + b1)
    {
#pragma unroll
        for (int p = 0; p < 2; ++p) {
            int o = wv + p * 4;
            float acc = b1[o];
            for (int ch = 0; ch < 256; ++ch) acc += w1[o * 320 + ch] * x_s[ch][m];
            for (int r = 0; r < 64; ++r) acc += w1[o * 320 + 256 + r] * hid_s[r][m];
            a_s[o][m] = fmaxf(acc, 0.f);
        }
    }
    __syncthreads();
    // phase 3: gate + write
    {
        for (int i = 0; i < 64; ++i) {
            int ch = wv * 64 + i;
            float g = b2[ch];
#pragma unroll
            for (int aa = 0; aa < 8; ++aa) g += w2[ch * 8 + aa] * a_s[aa][m];
            float gate = 1.f / (1.f + __expf(-g));
            XG[(size_t)(b * 256 + ch) * LL + m0 + m] = x_s[ch][m] * gate;
        }
    }
}

// ---------------------------------------------------------------------------
// Kernel E: conv3 (Cin=256 -> Cout=64) + BN + ReLU
// grid (B, L/64), block 256
__global__ __launch_bounds__(256) void kE(const float* __restrict__ XG,
                                          const float* __restrict__ pw,
                                          const float* __restrict__ bg,
                                          const float* __restrict__ bbe,
                                          const float* __restrict__ bm,
                                          const float* __restrict__ bv,
                                          float* __restrict__ Y1) {
    int b = blockIdx.x;
    int m0 = blockIdx.y * 64;
    __shared__ float xt[256][66];
    int t = threadIdx.x;
    for (int idx = t; idx < 256 * 66; idx += 256) {
        int ch = idx / 66, j = idx % 66;
        int l = m0 - 1 + j;
        xt[ch][j] = (l >= 0 && l < LL) ? XG[(size_t)(b * 256 + ch) * LL + l] : 0.f;
    }
    __syncthreads();
    int m = t & 63;
    int wv = t >> 6;
    for (int i = 0; i < 16; ++i) {
        int r = wv * 16 + i;
        float acc = 0.f;
        for (int ch = 0; ch < 256; ++ch) {
            const float* wp = pw + (size_t)(r * 256 + ch) * 3;
            acc += wp[0] * xt[ch][m] + wp[1] * xt[ch][m + 1] + wp[2] * xt[ch][m + 2];
        }
        float inv = bg[r] * rsqrtf(bv[r] + EPS);
        float y = acc * inv + (bbe[r] - bm[r] * inv);
        Y1[(size_t)(b * 64 + r) * LL + m0 + m] = fmaxf(y, 0.f);
    }
}

// ---------------------------------------------------------------------------
// Kernel F: conv3 (Cin=64 -> Cout=64) + BN + ReLU -> out
// grid (B, L/64), block 256
__global__ __launch_bounds__(256) void kF(const float* __restrict__ Y1,
                                          const float* __restrict__ pw,
                                          const float* __restrict__ bg,
                                          const float* __restrict__ bbe,
                                          const float* __restrict__ bm,
                                          const float* __restrict__ bv,
                                          float* __restrict__ out) {
    int b = blockIdx.x;
    int m0 = blockIdx.y * 64;
    __shared__ float yt[64][66];
    int t = threadIdx.x;
    for (int idx = t; idx < 64 * 66; idx += 256) {
        int ch = idx / 66, j = idx % 66;
        int l = m0 - 1 + j;
        yt[ch][j] = (l >= 0 && l < LL) ? Y1[(size_t)(b * 64 + ch) * LL + l] : 0.f;
    }
    __syncthreads();
    int m = t & 63;
    int wv = t >> 6;
    for (int i = 0; i < 16; ++i) {
        int r = wv * 16 + i;
        float acc = 0.f;
        for (int c = 0; c < 64; ++c) {
            const float* wp = pw + (size_t)(r * 64 + c) * 3;
            acc += wp[0] * yt[c][m] + wp[1] * yt[c][m + 1] + wp[2] * yt[c][m + 2];
        }
        float inv = bg[r] * rsqrtf(bv[r] + EPS);
        float y = acc * inv + (bbe[r] - bm[r] * inv);
        out[(size_t)(b * 64 + r) * LL + m0 + m] = fmaxf(y, 0.f);
    }
}

// ---------------------------------------------------------------------------
extern "C" void kernel_launch(void* const* d_in, const int* in_sizes, int n_in,
                              void* d_out, int out_size, void* d_ws, size_t ws_size,
                              hipStream_t stream) {
    (void)in_sizes; (void)n_in; (void)out_size; (void)ws_size;
    const float* inp    = (const float*)d_in[0];
    const float* hidden = (const float*)d_in[1];
    const float* key_w  = (const float*)d_in[2];
    const float* value_w= (const float*)d_in[3];
    const float* ca_w1  = (const float*)d_in[4];
    const float* ca_b1  = (const float*)d_in[5];
    const float* ca_w2  = (const float*)d_in[6];
    const float* ca_b2  = (const float*)d_in[7];
    const float* pw1    = (const float*)d_in[8];
    const float* bn1_g  = (const float*)d_in[9];
    const float* bn1_b  = (const float*)d_in[10];
    const float* bn1_m  = (const float*)d_in[11];
    const float* bn1_v  = (const float*)d_in[12];
    const float* pw2    = (const float*)d_in[13];
    const float* bn2_g  = (const float*)d_in[14];
    const float* bn2_b  = (const float*)d_in[15];
    const float* bn2_m  = (const float*)d_in[16];
    const float* bn2_v  = (const float*)d_in[17];

    float* ws = (float*)d_ws;
    const size_t KV = (size_t)HH * BB * CC * LL;    // 4,194,304 floats
    float* K = ws;
    float* V = ws + KV;
    float* U = ws + 2 * KV;                          // H*B*L
    float* W = U + (size_t)HH * BB * LL;             // H*B*L*5
    float* S = W + (size_t)HH * BB * LL * 5;         // H*B*C
    float* XG = K;   // alias: K dead after kB
    float* Y1 = V;   // alias: V dead after kD

    kA<<<dim3(HH * BB, LL / 256), 256, 0, stream>>>(inp, key_w, value_w, K, V);
    kB<<<dim3(HH * BB, LL / 128), 128, 0, stream>>>(K, hidden, U, W);
    kC<<<dim3(HH * BB), 256, 0, stream>>>(V, U, S);
    kD<<<dim3(BB, LL / 64), 256, 0, stream>>>(inp, hidden, V, U, W, S,
                                              ca_w1, ca_b1, ca_w2, ca_b2, XG);
    kE<<<dim3(BB, LL / 64), 256, 0, stream>>>(XG, pw1, bn1_g, bn1_b, bn1_m, bn1_v, Y1);
    kF<<<dim3(BB, LL / 64), 256, 0, stream>>>(Y1, pw2, bn2_g, bn2_b, bn2_m, bn2_v,
                                              (float*)d_out);
}

// Round 2
// 355.769 us; speedup vs baseline: 1.2829x; 1.2829x over previous
//
#include <hip/hip_runtime.h>
#include <hip/hip_bf16.h>
#include <math.h>

// Sizes
#define HH 4
#define BB 8
#define CC 64
#define RR 64
#define LL 2048
#define AA 8
#define HC 256   // H*C
#define EPS 1e-5f

// ---------------------------------------------------------------------------
// Kernel A: K = key_w[h] @ inputs[h,b]  (R x L), V = value_w[h] @ inputs[h,b]
// grid (H*B, L/256), block 256
__global__ __launch_bounds__(256) void kA(const float* __restrict__ inp,
                                          const float* __restrict__ kw,
                                          const float* __restrict__ vw,
                                          float* __restrict__ K,
                                          float* __restrict__ V) {
    int hb = blockIdx.x;
    int h = hb >> 3;
    int l0 = blockIdx.y * 256;
    __shared__ float in_s[64][256];
    const float* ibase = inp + (size_t)(hb * 64) * LL + l0;
    int t = threadIdx.x;
    for (int c = 0; c < 64; ++c) in_s[c][t] = ibase[c * LL + t];
    __syncthreads();
    const float* kwh = kw + h * 64 * 64;
    const float* vwh = vw + h * 64 * 64;
    float* Kb = K + (size_t)(hb * 64) * LL + l0;
    float* Vb = V + (size_t)(hb * 64) * LL + l0;
    for (int rb = 0; rb < 8; ++rb) {
        float accK[8], accV[8];
#pragma unroll
        for (int i = 0; i < 8; ++i) { accK[i] = 0.f; accV[i] = 0.f; }
        for (int c = 0; c < 64; ++c) {
            float x = in_s[c][t];
#pragma unroll
            for (int i = 0; i < 8; ++i) {
                accK[i] += kwh[(rb * 8 + i) * 64 + c] * x;
                accV[i] += vwh[(rb * 8 + i) * 64 + c] * x;
            }
        }
#pragma unroll
        for (int i = 0; i < 8; ++i) {
            Kb[(size_t)(rb * 8 + i) * LL + t] = accK[i];
            Vb[(size_t)(rb * 8 + i) * LL + t] = accV[i];
        }
    }
}

// ---------------------------------------------------------------------------
// Kernel B: banded softmax stats per (h,b,l): u and w[5]
// grid (H*B, L/128), block 128
__global__ __launch_bounds__(128) void kB(const float* __restrict__ K,
                                          const float* __restrict__ hidden,
                                          float* __restrict__ U,
                                          float* __restrict__ W) {
    int hb = blockIdx.x;
    int b = hb & 7;
    int l0 = blockIdx.y * 128;
    __shared__ float k_s[64][132];
    __shared__ float h_s[64][128];
    const float* Kb = K + (size_t)(hb * 64) * LL;
    int t = threadIdx.x;
    for (int idx = t; idx < 64 * 132; idx += 128) {
        int r = idx / 132, j = idx % 132;
        int m = l0 - 2 + j;
        k_s[r][j] = (m >= 0 && m < LL) ? Kb[(size_t)r * LL + m] : 0.f;
    }
    const float* hbp = hidden + (size_t)(b * 64) * LL + l0;
    for (int r = 0; r < 64; ++r) h_s[r][t] = hbp[(size_t)r * LL + t];
    __syncthreads();
    int l = l0 + t;
    float raw[5];
    float mx = 0.f;
    int nv = 0;
#pragma unroll
    for (int d = 0; d < 5; ++d) {
        int m = l + d - 2;
        bool valid = (m >= 0 && m < LL);
        float acc = 0.f;
        if (valid) {
            for (int r = 0; r < 64; ++r) acc += h_s[r][t] * k_s[r][t + d];
            acc *= 0.125f;   // q scale 1/sqrt(64)
            nv++;
            mx = fmaxf(mx, acc);
        }
        raw[d] = valid ? acc : -1e30f;
    }
    float e0 = __expf(-mx);
    float Z = (float)(LL - nv) * e0;
    float w[5];
#pragma unroll
    for (int d = 0; d < 5; ++d) {
        float e = (raw[d] > -1e29f) ? __expf(raw[d] - mx) : 0.f;
        w[d] = e;
        Z += e;
    }
    float inv = 1.f / Z;
    U[(size_t)hb * LL + l] = e0 * inv;
#pragma unroll
    for (int d = 0; d < 5; ++d) W[((size_t)hb * LL + l) * 5 + d] = w[d] * inv;
}

// ---------------------------------------------------------------------------
// Kernel C: S[hb][c] = sum_l V[hb][c][l] * U[hb][l]
// grid (H*B), block 256
__global__ __launch_bounds__(256) void kC(const float* __restrict__ V,
                                          const float* __restrict__ U,
                                          float* __restrict__ S) {
    int hb = blockIdx.x;
    int t = threadIdx.x;
    int c = t >> 2, sub = t & 3;
    const float* Vb = V + (size_t)(hb * 64 + c) * LL;
    const float* Ub = U + (size_t)hb * LL;
    float acc = 0.f;
    for (int l = sub; l < LL; l += 4) acc += Vb[l] * Ub[l];
    __shared__ float red[256];
    red[t] = acc;
    __syncthreads();
    if (sub == 0) S[hb * 64 + c] = red[t] + red[t + 1] + red[t + 2] + red[t + 3];
}

// ---------------------------------------------------------------------------
// Kernel D: val + residual -> x; channel attention -> gate; write XG
// grid (B, L/64), block 256
__global__ __launch_bounds__(256) void kD(const float* __restrict__ inp,
                                          const float* __restrict__ hidden,
                                          const float* __restrict__ V,
                                          const float* __restrict__ U,
                                          const float* __restrict__ W,
                                          const float* __restrict__ S,
                                          const float* __restrict__ w1,
                                          const float* __restrict__ b1,
                                          const float* __restrict__ w2,
                                          const float* __restrict__ b2,
                                          float* __restrict__ XG) {
    int b = blockIdx.x;
    int m0 = blockIdx.y * 64;
    __shared__ float x_s[256][64];
    __shared__ float hid_s[64][64];
    __shared__ float u_s[4][68];
    __shared__ float w_s[4][68][5];
    __shared__ float a_s[8][64];
    __shared__ float S_s[256];
    int t = threadIdx.x;
    int m = t & 63;
    int wv = t >> 6;  // wave id 0..3
    // stage hidden tile
    for (int i = 0; i < 16; ++i) {
        int r = wv * 16 + i;
        hid_s[r][m] = hidden[(size_t)(b * 64 + r) * LL + m0 + m];
    }
    // stage u, w (range [m0-2, m0+66))
    for (int idx = t; idx < 4 * 68; idx += 256) {
        int h = idx / 68, j = idx % 68;
        int l = m0 - 2 + j;
        bool v = (l >= 0 && l < LL);
        int hb = h * 8 + b;
        u_s[h][j] = v ? U[(size_t)hb * LL + l] : 0.f;
#pragma unroll
        for (int d = 0; d < 5; ++d)
            w_s[h][j][d] = v ? W[((size_t)hb * LL + l) * 5 + d] : 0.f;
    }
    // stage S
    S_s[t] = S[((t >> 6) * 8 + b) * 64 + (t & 63)];
    __syncthreads();
    // phase 1: x[ch][m] = inputs + S + banded correction
    {
        int h = wv;  // wave handles one head's 64 channels
        int hb = h * 8 + b;
        for (int c = 0; c < 64; ++c) {
            int ch = h * 64 + c;
            float val = S_s[ch];
#pragma unroll
            for (int o = -2; o <= 2; ++o) {
                int l = m0 + m - o;
                if (l >= 0 && l < LL) {
                    int j = l - (m0 - 2);
                    val += V[(size_t)(hb * 64 + c) * LL + l] * (w_s[h][j][o + 2] - u_s[h][j]);
                }
            }
            x_s[ch][m] = inp[(size_t)(hb * 64 + c) * LL + m0 + m] + val;
        }
    }
    __syncthreads();
    // phase 2: a[o][m] = relu(ca_w1 . cat + b1)
    {
#pragma unroll
        for (int p = 0; p < 2; ++p) {
            int o = wv + p * 4;
            float acc = b1[o];
            for (int ch = 0; ch < 256; ++ch) acc += w1[o * 320 + ch] * x_s[ch][m];
            for (int r = 0; r < 64; ++r) acc += w1[o * 320 + 256 + r] * hid_s[r][m];
            a_s[o][m] = fmaxf(acc, 0.f);
        }
    }
    __syncthreads();
    // phase 3: gate + write
    {
        for (int i = 0; i < 64; ++i) {
            int ch = wv * 64 + i;
            float g = b2[ch];
#pragma unroll
            for (int aa = 0; aa < 8; ++aa) g += w2[ch * 8 + aa] * a_s[aa][m];
            float gate = 1.f / (1.f + __expf(-g));
            XG[(size_t)(b * 256 + ch) * LL + m0 + m] = x_s[ch][m] * gate;
        }
    }
}

// ---------------------------------------------------------------------------
// Kernel W: fold BN into conv weights and transpose to [ch][tap][r] layout.
// wE[ch][tap][r] = pw1[r][ch][tap] * inv1[r]; biasE[r] = bn1_b - bn1_m*inv1
// wF[c][tap][r]  = pw2[r][c][tap]  * inv2[r]; biasF[r] = bn2_b - bn2_m*inv2
// grid 48, block 256
__global__ __launch_bounds__(256) void kW(const float* __restrict__ pw1,
                                          const float* __restrict__ g1,
                                          const float* __restrict__ b1,
                                          const float* __restrict__ m1,
                                          const float* __restrict__ v1,
                                          const float* __restrict__ pw2,
                                          const float* __restrict__ g2,
                                          const float* __restrict__ b2,
                                          const float* __restrict__ m2,
                                          const float* __restrict__ v2,
                                          float* __restrict__ wE,
                                          float* __restrict__ biasE,
                                          float* __restrict__ wF,
                                          float* __restrict__ biasF) {
    int tid = blockIdx.x * 256 + threadIdx.x;
    int stride = gridDim.x * 256;
    for (int idx = tid; idx < 256 * 3 * 64; idx += stride) {
        int r = idx & 63;
        int tap = (idx >> 6) % 3;
        int ch = idx / 192;
        float inv = g1[r] * rsqrtf(v1[r] + EPS);
        wE[idx] = pw1[(r * 256 + ch) * 3 + tap] * inv;
    }
    for (int idx = tid; idx < 64 * 3 * 64; idx += stride) {
        int r = idx & 63;
        int tap = (idx >> 6) % 3;
        int c = idx / 192;
        float inv = g2[r] * rsqrtf(v2[r] + EPS);
        wF[idx] = pw2[(r * 64 + c) * 3 + tap] * inv;
    }
    if (tid < 64) {
        float inv1 = g1[tid] * rsqrtf(v1[tid] + EPS);
        biasE[tid] = b1[tid] - m1[tid] * inv1;
        float inv2 = g2[tid] * rsqrtf(v2[tid] + EPS);
        biasF[tid] = b2[tid] - m2[tid] * inv2;
    }
}

// ---------------------------------------------------------------------------
// Kernel E: conv3 (Cin=256 -> Cout=64) + folded BN + ReLU
// grid (B, L/64), block 512. Wave w handles r = w*8 .. w*8+7, lane = m.
// Inverted loop: ch outer (hoist 3 LDS reads), 8 accumulators,
// weights via wave-uniform s_load from pre-transposed wE[ch][tap][r].
__global__ __launch_bounds__(512) void kE(const float* __restrict__ XG,
                                          const float* __restrict__ wE,
                                          const float* __restrict__ biasE,
                                          float* __restrict__ Y1) {
    int b = blockIdx.x;
    int m0 = blockIdx.y * 64;
    __shared__ float xt[256][66];
    int t = threadIdx.x;
    for (int idx = t; idx < 256 * 66; idx += 512) {
        int ch = idx / 66, j = idx % 66;
        int l = m0 - 1 + j;
        xt[ch][j] = (l >= 0 && l < LL) ? XG[(size_t)(b * 256 + ch) * LL + l] : 0.f;
    }
    __syncthreads();
    int m = t & 63;
    int w = t >> 6;        // 0..7
    int rbase = w * 8;
    float acc[8];
#pragma unroll
    for (int i = 0; i < 8; ++i) acc[i] = 0.f;
    for (int ch = 0; ch < 256; ++ch) {
        float x0 = xt[ch][m];
        float x1 = xt[ch][m + 1];
        float x2 = xt[ch][m + 2];
        const float* wp = wE + ch * 192 + rbase;   // [ch][tap][r]
#pragma unroll
        for (int i = 0; i < 8; ++i) {
            acc[i] += wp[i] * x0 + wp[64 + i] * x1 + wp[128 + i] * x2;
        }
    }
#pragma unroll
    for (int i = 0; i < 8; ++i) {
        int r = rbase + i;
        Y1[(size_t)(b * 64 + r) * LL + m0 + m] = fmaxf(acc[i] + biasE[r], 0.f);
    }
}

// ---------------------------------------------------------------------------
// Kernel F: conv3 (Cin=64 -> Cout=64) + folded BN + ReLU -> out
// grid (B, L/64), block 512, same structure as kE
__global__ __launch_bounds__(512) void kF(const float* __restrict__ Y1,
                                          const float* __restrict__ wF,
                                          const float* __restrict__ biasF,
                                          float* __restrict__ out) {
    int b = blockIdx.x;
    int m0 = blockIdx.y * 64;
    __shared__ float yt[64][66];
    int t = threadIdx.x;
    for (int idx = t; idx < 64 * 66; idx += 512) {
        int ch = idx / 66, j = idx % 66;
        int l = m0 - 1 + j;
        yt[ch][j] = (l >= 0 && l < LL) ? Y1[(size_t)(b * 64 + ch) * LL + l] : 0.f;
    }
    __syncthreads();
    int m = t & 63;
    int w = t >> 6;
    int rbase = w * 8;
    float acc[8];
#pragma unroll
    for (int i = 0; i < 8; ++i) acc[i] = 0.f;
    for (int c = 0; c < 64; ++c) {
        float x0 = yt[c][m];
        float x1 = yt[c][m + 1];
        float x2 = yt[c][m + 2];
        const float* wp = wF + c * 192 + rbase;    // [c][tap][r]
#pragma unroll
        for (int i = 0; i < 8; ++i) {
            acc[i] += wp[i] * x0 + wp[64 + i] * x1 + wp[128 + i] * x2;
        }
    }
#pragma unroll
    for (int i = 0; i < 8; ++i) {
        int r = rbase + i;
        out[(size_t)(b * 64 + r) * LL + m0 + m] = fmaxf(acc[i] + biasF[r], 0.f);
    }
}

// ---------------------------------------------------------------------------
extern "C" void kernel_launch(void* const* d_in, const int* in_sizes, int n_in,
                              void* d_out, int out_size, void* d_ws, size_t ws_size,
                              hipStream_t stream) {
    (void)in_sizes; (void)n_in; (void)out_size; (void)ws_size;
    const float* inp    = (const float*)d_in[0];
    const float* hidden = (const float*)d_in[1];
    const float* key_w  = (const float*)d_in[2];
    const float* value_w= (const float*)d_in[3];
    const float* ca_w1  = (const float*)d_in[4];
    const float* ca_b1  = (const float*)d_in[5];
    const float* ca_w2  = (const float*)d_in[6];
    const float* ca_b2  = (const float*)d_in[7];
    const float* pw1    = (const float*)d_in[8];
    const float* bn1_g  = (const float*)d_in[9];
    const float* bn1_b  = (const float*)d_in[10];
    const float* bn1_m  = (const float*)d_in[11];
    const float* bn1_v  = (const float*)d_in[12];
    const float* pw2    = (const float*)d_in[13];
    const float* bn2_g  = (const float*)d_in[14];
    const float* bn2_b  = (const float*)d_in[15];
    const float* bn2_m  = (const float*)d_in[16];
    const float* bn2_v  = (const float*)d_in[17];

    float* ws = (float*)d_ws;
    const size_t KV = (size_t)HH * BB * CC * LL;    // 4,194,304 floats
    float* K = ws;
    float* V = ws + KV;
    float* U = ws + 2 * KV;                          // H*B*L = 65536
    float* W = U + (size_t)HH * BB * LL;             // H*B*L*5 = 327680
    float* S = W + (size_t)HH * BB * LL * 5;         // H*B*C = 2048
    float* wE    = S + (size_t)HH * BB * CC;         // 256*3*64 = 49152
    float* biasE = wE + 256 * 3 * 64;                // 64
    float* wF    = biasE + 64;                       // 64*3*64 = 12288
    float* biasF = wF + 64 * 3 * 64;                 // 64
    float* XG = K;   // alias: K dead after kB
    float* Y1 = V;   // alias: V dead after kD

    kW<<<dim3(48), 256, 0, stream>>>(pw1, bn1_g, bn1_b, bn1_m, bn1_v,
                                     pw2, bn2_g, bn2_b, bn2_m, bn2_v,
                                     wE, biasE, wF, biasF);
    kA<<<dim3(HH * BB, LL / 256), 256, 0, stream>>>(inp, key_w, value_w, K, V);
    kB<<<dim3(HH * BB, LL / 128), 128, 0, stream>>>(K, hidden, U, W);
    kC<<<dim3(HH * BB), 256, 0, stream>>>(V, U, S);
    kD<<<dim3(BB, LL / 64), 256, 0, stream>>>(inp, hidden, V, U, W, S,
                                              ca_w1, ca_b1, ca_w2, ca_b2, XG);
    kE<<<dim3(BB, LL / 64), 512, 0, stream>>>(XG, wE, biasE, Y1);
    kF<<<dim3(BB, LL / 64), 512, 0, stream>>>(Y1, wF, biasF, (float*)d_out);
}

// Round 3
// 232.703 us; speedup vs baseline: 1.9614x; 1.5289x over previous
//
#include <hip/hip_runtime.h>
#include <hip/hip_bf16.h>
#include <math.h>

// Sizes
#define HH 4
#define BB 8
#define CC 64
#define RR 64
#define LL 2048
#define AA 8
#define HC 256   // H*C
#define EPS 1e-5f

// ---------------------------------------------------------------------------
// Kernel A: fused K/V GEMM. Out rows 0..63 = K = key_w[h] @ inputs[h,b],
// rows 64..127 = V. grid (H*B, L/64) = (32,32), block 256 (4 waves).
// LDS: in_s[64][64] (16KB) + wT[64][128] (32KB) -> 48KB, 2+ blocks/CU.
// Lane tiling: mg=lane&15 -> 4 l's, rg=lane>>4 -> 8 rows; acc[8][4].
__global__ __launch_bounds__(256) void kA(const float* __restrict__ inp,
                                          const float* __restrict__ kw,
                                          const float* __restrict__ vw,
                                          float* __restrict__ K,
                                          float* __restrict__ V) {
    int hb = blockIdx.x;
    int h = hb >> 3;
    int l0 = blockIdx.y * 64;
    __shared__ float in_s[64][64];
    __shared__ float wT[64][128];   // [c][row]; row<64: key, row>=64: value
    int t = threadIdx.x;
    const float* kwh = kw + h * 4096;
    const float* vwh = vw + h * 4096;
    for (int idx = t; idx < 4096; idx += 256) {
        int r = idx >> 6, c = idx & 63;
        wT[c][r] = kwh[idx];        // kwh[r*64+c]
        wT[c][64 + r] = vwh[idx];
    }
    for (int idx = t; idx < 4096; idx += 256) {
        int c = idx >> 6, j = idx & 63;
        in_s[c][j] = inp[(size_t)(hb * 64 + c) * LL + l0 + j];
    }
    __syncthreads();
    int w = t >> 6, lane = t & 63;
    int mg = lane & 15, rg = lane >> 4;
    int rowbase = w * 32 + rg * 8;
    int jx = mg * 4;
    float acc[8][4] = {};
    for (int c = 0; c < 64; ++c) {
        float4 x = *(const float4*)&in_s[c][jx];
        float4 wa = *(const float4*)&wT[c][rowbase];
        float4 wb = *(const float4*)&wT[c][rowbase + 4];
        float wv[8] = {wa.x, wa.y, wa.z, wa.w, wb.x, wb.y, wb.z, wb.w};
        float xv[4] = {x.x, x.y, x.z, x.w};
#pragma unroll
        for (int i = 0; i < 8; ++i)
#pragma unroll
            for (int k = 0; k < 4; ++k)
                acc[i][k] += wv[i] * xv[k];
    }
#pragma unroll
    for (int i = 0; i < 8; ++i) {
        int row = rowbase + i;
        float* dst = (row < 64 ? K : V);
        float4 o = {acc[i][0], acc[i][1], acc[i][2], acc[i][3]};
        *(float4*)&dst[(size_t)(hb * 64 + (row & 63)) * LL + l0 + jx] = o;
    }
}

// ---------------------------------------------------------------------------
// Kernel B: banded softmax stats per (h,b,l): u and w[5]
// grid (H*B, L/128), block 128
__global__ __launch_bounds__(128) void kB(const float* __restrict__ K,
                                          const float* __restrict__ hidden,
                                          float* __restrict__ U,
                                          float* __restrict__ W) {
    int hb = blockIdx.x;
    int b = hb & 7;
    int l0 = blockIdx.y * 128;
    __shared__ float k_s[64][132];
    __shared__ float h_s[64][128];
    const float* Kb = K + (size_t)(hb * 64) * LL;
    int t = threadIdx.x;
    for (int idx = t; idx < 64 * 132; idx += 128) {
        int r = idx / 132, j = idx % 132;
        int m = l0 - 2 + j;
        k_s[r][j] = (m >= 0 && m < LL) ? Kb[(size_t)r * LL + m] : 0.f;
    }
    const float* hbp = hidden + (size_t)(b * 64) * LL + l0;
    for (int r = 0; r < 64; ++r) h_s[r][t] = hbp[(size_t)r * LL + t];
    __syncthreads();
    int l = l0 + t;
    float raw[5];
    float mx = 0.f;
    int nv = 0;
#pragma unroll
    for (int d = 0; d < 5; ++d) {
        int m = l + d - 2;
        bool valid = (m >= 0 && m < LL);
        float acc = 0.f;
        if (valid) {
            for (int r = 0; r < 64; ++r) acc += h_s[r][t] * k_s[r][t + d];
            acc *= 0.125f;   // q scale 1/sqrt(64)
            nv++;
            mx = fmaxf(mx, acc);
        }
        raw[d] = valid ? acc : -1e30f;
    }
    float e0 = __expf(-mx);
    float Z = (float)(LL - nv) * e0;
    float w[5];
#pragma unroll
    for (int d = 0; d < 5; ++d) {
        float e = (raw[d] > -1e29f) ? __expf(raw[d] - mx) : 0.f;
        w[d] = e;
        Z += e;
    }
    float inv = 1.f / Z;
    U[(size_t)hb * LL + l] = e0 * inv;
#pragma unroll
    for (int d = 0; d < 5; ++d) W[((size_t)hb * LL + l) * 5 + d] = w[d] * inv;
}

// ---------------------------------------------------------------------------
// Kernel C: S[hb][c] = sum_l V[hb][c][l] * U[hb][l]
// grid (H*B), block 256
__global__ __launch_bounds__(256) void kC(const float* __restrict__ V,
                                          const float* __restrict__ U,
                                          float* __restrict__ S) {
    int hb = blockIdx.x;
    int t = threadIdx.x;
    int c = t >> 2, sub = t & 3;
    const float* Vb = V + (size_t)(hb * 64 + c) * LL;
    const float* Ub = U + (size_t)hb * LL;
    float acc = 0.f;
    for (int l = sub; l < LL; l += 4) acc += Vb[l] * Ub[l];
    __shared__ float red[256];
    red[t] = acc;
    __syncthreads();
    if (sub == 0) S[hb * 64 + c] = red[t] + red[t + 1] + red[t + 2] + red[t + 3];
}

// ---------------------------------------------------------------------------
// Kernel D: val + residual -> x; channel attention -> gate; write XG
// grid (B, L/64), block 256 (4 waves). m = t&63, wv = t>>6.
__global__ __launch_bounds__(256) void kD(const float* __restrict__ inp,
                                          const float* __restrict__ hidden,
                                          const float* __restrict__ V,
                                          const float* __restrict__ U,
                                          const float* __restrict__ W,
                                          const float* __restrict__ S,
                                          const float* __restrict__ w1,
                                          const float* __restrict__ b1,
                                          const float* __restrict__ w2,
                                          const float* __restrict__ b2,
                                          float* __restrict__ XG) {
    int b = blockIdx.x;
    int m0 = blockIdx.y * 64;
    __shared__ float x_s[256][64];     // gated input to channel-attn (64KB)
    __shared__ float hid_s[64][64];    // 16KB
    __shared__ float Vt[64][68];       // one head's V tile with halo 2 (17.4KB)
    __shared__ float dw_s[4][68][5];   // (w - u) per head/row (5.4KB)
    __shared__ float S_s[256];
    __shared__ float w1T[320][8];      // w1T[ch][o] (10.2KB)
    __shared__ float w2T[256][8];      // w2[ch][a] layout (8.2KB)
    __shared__ float b1_s[8];
    __shared__ float b2_s[256];
    __shared__ float partial[3][64][8];
    __shared__ float a_s[64][8];
    int t = threadIdx.x;
    int m = t & 63;
    int wv = t >> 6;
    // --- phase 0 staging ---
    for (int i = 0; i < 16; ++i) {
        int r = wv * 16 + i;
        hid_s[r][m] = hidden[(size_t)(b * 64 + r) * LL + m0 + m];
    }
    for (int idx = t; idx < 4 * 68; idx += 256) {
        int h = idx / 68, j = idx % 68;
        int l = m0 - 2 + j;
        int hb = h * 8 + b;
        if (l >= 0 && l < LL) {
            float u = U[(size_t)hb * LL + l];
            const float* wp = &W[((size_t)hb * LL + l) * 5];
#pragma unroll
            for (int d = 0; d < 5; ++d) dw_s[h][j][d] = wp[d] - u;
        } else {
#pragma unroll
            for (int d = 0; d < 5; ++d) dw_s[h][j][d] = 0.f;
        }
    }
    S_s[t] = S[(wv * 8 + b) * 64 + m];
    for (int idx = t; idx < 2560; idx += 256)
        w1T[idx >> 3][idx & 7] = w1[(idx & 7) * 320 + (idx >> 3)];
    for (int idx = t; idx < 2048; idx += 256)
        ((float*)w2T)[idx] = w2[idx];
    if (t < 8) b1_s[t] = b1[t];
    b2_s[t] = b2[t];
    // --- phase 1: x = inputs + S + banded correction, per head ---
    for (int h = 0; h < 4; ++h) {
        __syncthreads();   // previous head's compute done (Vt reusable)
        int hb8 = h * 8 + b;
        for (int idx = t; idx < 64 * 68; idx += 256) {
            int c = idx / 68, j = idx % 68;
            int l = m0 - 2 + j;
            Vt[c][j] = (l >= 0 && l < LL) ? V[(size_t)(hb8 * 64 + c) * LL + l] : 0.f;
        }
        __syncthreads();   // Vt ready (also covers phase-0 staging on h==0)
        float dwv[5];
#pragma unroll
        for (int d = 0; d < 5; ++d) dwv[d] = dw_s[h][m + 4 - d][d];
        for (int c = wv * 16; c < wv * 16 + 16; ++c) {
            int ch = h * 64 + c;
            float v0 = Vt[c][m], v1 = Vt[c][m + 1], v2 = Vt[c][m + 2];
            float v3 = Vt[c][m + 3], v4 = Vt[c][m + 4];
            float val = S_s[ch] + v4 * dwv[0] + v3 * dwv[1] + v2 * dwv[2]
                      + v1 * dwv[3] + v0 * dwv[4];
            x_s[ch][m] = inp[(size_t)(hb8 * 64 + c) * LL + m0 + m] + val;
        }
    }
    __syncthreads();
    // --- phase 2: a[m][o] = relu(w1 . cat + b1), split-K over 4 waves ---
    float acc2[8] = {};
    int c0 = wv * 80;
    for (int cc = 0; cc < 80; ++cc) {
        int ch = c0 + cc;
        float xv = (ch < 256) ? x_s[ch][m] : hid_s[ch - 256][m];
        float4 wa = *(const float4*)&w1T[ch][0];
        float4 wb = *(const float4*)&w1T[ch][4];
        acc2[0] += wa.x * xv; acc2[1] += wa.y * xv;
        acc2[2] += wa.z * xv; acc2[3] += wa.w * xv;
        acc2[4] += wb.x * xv; acc2[5] += wb.y * xv;
        acc2[6] += wb.z * xv; acc2[7] += wb.w * xv;
    }
    if (wv > 0) {
#pragma unroll
        for (int o = 0; o < 8; ++o) partial[wv - 1][m][o] = acc2[o];
    }
    __syncthreads();
    if (wv == 0) {
#pragma unroll
        for (int o = 0; o < 8; ++o) {
            float a = acc2[o] + partial[0][m][o] + partial[1][m][o]
                    + partial[2][m][o] + b1_s[o];
            a_s[m][o] = fmaxf(a, 0.f);
        }
    }
    __syncthreads();
    // --- phase 3: gate + write ---
    float4 a0 = *(const float4*)&a_s[m][0];
    float4 a1 = *(const float4*)&a_s[m][4];
    for (int i = 0; i < 64; ++i) {
        int ch = wv * 64 + i;
        float4 wa = *(const float4*)&w2T[ch][0];
        float4 wb = *(const float4*)&w2T[ch][4];
        float g = b2_s[ch] + a0.x * wa.x + a0.y * wa.y + a0.z * wa.z + a0.w * wa.w
                + a1.x * wb.x + a1.y * wb.y + a1.z * wb.z + a1.w * wb.w;
        float gate = 1.f / (1.f + __expf(-g));
        XG[(size_t)(b * 256 + ch) * LL + m0 + m] = x_s[ch][m] * gate;
    }
}

// ---------------------------------------------------------------------------
// Kernel W: fold BN into conv weights and transpose to [ch][tap][r] layout.
__global__ __launch_bounds__(256) void kW(const float* __restrict__ pw1,
                                          const float* __restrict__ g1,
                                          const float* __restrict__ b1,
                                          const float* __restrict__ m1,
                                          const float* __restrict__ v1,
                                          const float* __restrict__ pw2,
                                          const float* __restrict__ g2,
                                          const float* __restrict__ b2,
                                          const float* __restrict__ m2,
                                          const float* __restrict__ v2,
                                          float* __restrict__ wE,
                                          float* __restrict__ biasE,
                                          float* __restrict__ wF,
                                          float* __restrict__ biasF) {
    int tid = blockIdx.x * 256 + threadIdx.x;
    int stride = gridDim.x * 256;
    for (int idx = tid; idx < 256 * 3 * 64; idx += stride) {
        int r = idx & 63;
        int tap = (idx >> 6) % 3;
        int ch = idx / 192;
        float inv = g1[r] * rsqrtf(v1[r] + EPS);
        wE[idx] = pw1[(r * 256 + ch) * 3 + tap] * inv;
    }
    for (int idx = tid; idx < 64 * 3 * 64; idx += stride) {
        int r = idx & 63;
        int tap = (idx >> 6) % 3;
        int c = idx / 192;
        float inv = g2[r] * rsqrtf(v2[r] + EPS);
        wF[idx] = pw2[(r * 64 + c) * 3 + tap] * inv;
    }
    if (tid < 64) {
        float inv1 = g1[tid] * rsqrtf(v1[tid] + EPS);
        biasE[tid] = b1[tid] - m1[tid] * inv1;
        float inv2 = g2[tid] * rsqrtf(v2[tid] + EPS);
        biasF[tid] = b2[tid] - m2[tid] * inv2;
    }
}

// ---------------------------------------------------------------------------
// kConv<CIN>: conv3 (CIN -> 64) + folded BN + ReLU.
// grid (B, L/64), block 256 (4 waves). Wave w: r in [w*16, w*16+16).
// Lane: mg=lane&15 -> m block of 4, rg=lane>>4 -> r block of 4. acc[4][4].
// LDS: xt[CIN][68] + 64-ch weight chunk [64][3][64] (48KB).
template <int CIN>
__global__ __launch_bounds__(256) void kConv(const float* __restrict__ X,
                                             const float* __restrict__ wT,
                                             const float* __restrict__ bias,
                                             float* __restrict__ out) {
    int b = blockIdx.x;
    int m0 = blockIdx.y * 64;
    __shared__ float xt[CIN][68];
    __shared__ float wch[64 * 192];
    int t = threadIdx.x;
    for (int idx = t; idx < CIN * 68; idx += 256) {
        int ch = idx / 68, j = idx % 68;
        int l = m0 - 2 + j;
        xt[ch][j] = (l >= 0 && l < LL) ? X[(size_t)(b * CIN + ch) * LL + l] : 0.f;
    }
    int w = t >> 6, lane = t & 63;
    int mg = lane & 15, rg = lane >> 4;
    int rbase = w * 16 + rg * 4;
    int jx = mg * 4;
    float acc[4][4] = {};
    for (int p = 0; p < CIN / 64; ++p) {
        __syncthreads();     // xt ready (p=0) / previous chunk's compute done
        for (int idx = t; idx < 64 * 192; idx += 256)
            wch[idx] = wT[p * 64 * 192 + idx];
        __syncthreads();
        for (int cc = 0; cc < 64; ++cc) {
            int ch = p * 64 + cc;
            float4 xa = *(const float4*)&xt[ch][jx];
            float4 xb = *(const float4*)&xt[ch][jx + 4];
            float xv[8] = {xa.x, xa.y, xa.z, xa.w, xb.x, xb.y, xb.z, xb.w};
            float4 w0 = *(const float4*)&wch[cc * 192 + rbase];
            float4 w1 = *(const float4*)&wch[cc * 192 + 64 + rbase];
            float4 w2 = *(const float4*)&wch[cc * 192 + 128 + rbase];
            float wt[3][4] = {{w0.x, w0.y, w0.z, w0.w},
                              {w1.x, w1.y, w1.z, w1.w},
                              {w2.x, w2.y, w2.z, w2.w}};
#pragma unroll
            for (int k = 0; k < 4; ++k) {
#pragma unroll
                for (int tap = 0; tap < 3; ++tap) {
                    float xvv = xv[k + tap + 1];   // x[m + k + tap - 1]
                    acc[0][k] += wt[tap][0] * xvv;
                    acc[1][k] += wt[tap][1] * xvv;
                    acc[2][k] += wt[tap][2] * xvv;
                    acc[3][k] += wt[tap][3] * xvv;
                }
            }
        }
    }
#pragma unroll
    for (int rr = 0; rr < 4; ++rr) {
        int r = rbase + rr;
        float bs = bias[r];
        float4 o;
        o.x = fmaxf(acc[rr][0] + bs, 0.f);
        o.y = fmaxf(acc[rr][1] + bs, 0.f);
        o.z = fmaxf(acc[rr][2] + bs, 0.f);
        o.w = fmaxf(acc[rr][3] + bs, 0.f);
        *(float4*)&out[(size_t)(b * 64 + r) * LL + m0 + jx] = o;
    }
}

// ---------------------------------------------------------------------------
extern "C" void kernel_launch(void* const* d_in, const int* in_sizes, int n_in,
                              void* d_out, int out_size, void* d_ws, size_t ws_size,
                              hipStream_t stream) {
    (void)in_sizes; (void)n_in; (void)out_size; (void)ws_size;
    const float* inp    = (const float*)d_in[0];
    const float* hidden = (const float*)d_in[1];
    const float* key_w  = (const float*)d_in[2];
    const float* value_w= (const float*)d_in[3];
    const float* ca_w1  = (const float*)d_in[4];
    const float* ca_b1  = (const float*)d_in[5];
    const float* ca_w2  = (const float*)d_in[6];
    const float* ca_b2  = (const float*)d_in[7];
    const float* pw1    = (const float*)d_in[8];
    const float* bn1_g  = (const float*)d_in[9];
    const float* bn1_b  = (const float*)d_in[10];
    const float* bn1_m  = (const float*)d_in[11];
    const float* bn1_v  = (const float*)d_in[12];
    const float* pw2    = (const float*)d_in[13];
    const float* bn2_g  = (const float*)d_in[14];
    const float* bn2_b  = (const float*)d_in[15];
    const float* bn2_m  = (const float*)d_in[16];
    const float* bn2_v  = (const float*)d_in[17];

    float* ws = (float*)d_ws;
    const size_t KV = (size_t)HH * BB * CC * LL;    // 4,194,304 floats
    float* K = ws;
    float* V = ws + KV;
    float* U = ws + 2 * KV;                          // H*B*L = 65536
    float* W = U + (size_t)HH * BB * LL;             // H*B*L*5 = 327680
    float* S = W + (size_t)HH * BB * LL * 5;         // H*B*C = 2048
    float* wE    = S + (size_t)HH * BB * CC;         // 256*3*64 = 49152
    float* biasE = wE + 256 * 3 * 64;                // 64
    float* wF    = biasE + 64;                       // 64*3*64 = 12288
    float* biasF = wF + 64 * 3 * 64;                 // 64
    float* XG = K;   // alias: K dead after kB
    float* Y1 = V;   // alias: V dead after kD

    kW<<<dim3(48), 256, 0, stream>>>(pw1, bn1_g, bn1_b, bn1_m, bn1_v,
                                     pw2, bn2_g, bn2_b, bn2_m, bn2_v,
                                     wE, biasE, wF, biasF);
    kA<<<dim3(HH * BB, LL / 64), 256, 0, stream>>>(inp, key_w, value_w, K, V);
    kB<<<dim3(HH * BB, LL / 128), 128, 0, stream>>>(K, hidden, U, W);
    kC<<<dim3(HH * BB), 256, 0, stream>>>(V, U, S);
    kD<<<dim3(BB, LL / 64), 256, 0, stream>>>(inp, hidden, V, U, W, S,
                                              ca_w1, ca_b1, ca_w2, ca_b2, XG);
    kConv<256><<<dim3(BB, LL / 64), 256, 0, stream>>>(XG, wE, biasE, Y1);
    kConv<64><<<dim3(BB, LL / 64), 256, 0, stream>>>(Y1, wF, biasF, (float*)d_out);
}

// Round 4
// 188.385 us; speedup vs baseline: 2.4229x; 1.2353x over previous
//
#include <hip/hip_runtime.h>
#include <hip/hip_bf16.h>
#include <math.h>

// Sizes
#define HH 4
#define BB 8
#define CC 64
#define RR 64
#define LL 2048
#define AA 8
#define HC 256   // H*C
#define EPS 1e-5f

// ---------------------------------------------------------------------------
// Kernel A: fused K/V GEMM. Out rows 0..63 = K = key_w[h] @ inputs[h,b],
// rows 64..127 = V. grid (H*B, L/64) = (32,32), block 256 (4 waves).
__global__ __launch_bounds__(256) void kA(const float* __restrict__ inp,
                                          const float* __restrict__ kw,
                                          const float* __restrict__ vw,
                                          float* __restrict__ K,
                                          float* __restrict__ V) {
    int hb = blockIdx.x;
    int h = hb >> 3;
    int l0 = blockIdx.y * 64;
    __shared__ float in_s[64][64];
    __shared__ float wT[64][128];   // [c][row]; row<64: key, row>=64: value
    int t = threadIdx.x;
    const float* kwh = kw + h * 4096;
    const float* vwh = vw + h * 4096;
    for (int idx = t; idx < 4096; idx += 256) {
        int r = idx >> 6, c = idx & 63;
        wT[c][r] = kwh[idx];        // kwh[r*64+c]
        wT[c][64 + r] = vwh[idx];
    }
    for (int idx = t; idx < 4096; idx += 256) {
        int c = idx >> 6, j = idx & 63;
        in_s[c][j] = inp[(size_t)(hb * 64 + c) * LL + l0 + j];
    }
    __syncthreads();
    int w = t >> 6, lane = t & 63;
    int mg = lane & 15, rg = lane >> 4;
    int rowbase = w * 32 + rg * 8;
    int jx = mg * 4;
    float acc[8][4] = {};
    for (int c = 0; c < 64; ++c) {
        float4 x = *(const float4*)&in_s[c][jx];
        float4 wa = *(const float4*)&wT[c][rowbase];
        float4 wb = *(const float4*)&wT[c][rowbase + 4];
        float wv[8] = {wa.x, wa.y, wa.z, wa.w, wb.x, wb.y, wb.z, wb.w};
        float xv[4] = {x.x, x.y, x.z, x.w};
#pragma unroll
        for (int i = 0; i < 8; ++i)
#pragma unroll
            for (int k = 0; k < 4; ++k)
                acc[i][k] += wv[i] * xv[k];
    }
#pragma unroll
    for (int i = 0; i < 8; ++i) {
        int row = rowbase + i;
        float* dst = (row < 64 ? K : V);
        float4 o = {acc[i][0], acc[i][1], acc[i][2], acc[i][3]};
        *(float4*)&dst[(size_t)(hb * 64 + (row & 63)) * LL + l0 + jx] = o;
    }
}

// ---------------------------------------------------------------------------
// Kernel B: banded softmax stats per (h,b,l): u and w[5]
// grid (H*B, L/128), block 128
__global__ __launch_bounds__(128) void kB(const float* __restrict__ K,
                                          const float* __restrict__ hidden,
                                          float* __restrict__ U,
                                          float* __restrict__ W) {
    int hb = blockIdx.x;
    int b = hb & 7;
    int l0 = blockIdx.y * 128;
    __shared__ float k_s[64][132];
    __shared__ float h_s[64][128];
    const float* Kb = K + (size_t)(hb * 64) * LL;
    int t = threadIdx.x;
    for (int idx = t; idx < 64 * 132; idx += 128) {
        int r = idx / 132, j = idx % 132;
        int m = l0 - 2 + j;
        k_s[r][j] = (m >= 0 && m < LL) ? Kb[(size_t)r * LL + m] : 0.f;
    }
    const float* hbp = hidden + (size_t)(b * 64) * LL + l0;
    for (int r = 0; r < 64; ++r) h_s[r][t] = hbp[(size_t)r * LL + t];
    __syncthreads();
    int l = l0 + t;
    float raw[5];
    float mx = 0.f;
    int nv = 0;
#pragma unroll
    for (int d = 0; d < 5; ++d) {
        int m = l + d - 2;
        bool valid = (m >= 0 && m < LL);
        float acc = 0.f;
        if (valid) {
            for (int r = 0; r < 64; ++r) acc += h_s[r][t] * k_s[r][t + d];
            acc *= 0.125f;   // q scale 1/sqrt(64)
            nv++;
            mx = fmaxf(mx, acc);
        }
        raw[d] = valid ? acc : -1e30f;
    }
    float e0 = __expf(-mx);
    float Z = (float)(LL - nv) * e0;
    float w[5];
#pragma unroll
    for (int d = 0; d < 5; ++d) {
        float e = (raw[d] > -1e29f) ? __expf(raw[d] - mx) : 0.f;
        w[d] = e;
        Z += e;
    }
    float inv = 1.f / Z;
    U[(size_t)hb * LL + l] = e0 * inv;
#pragma unroll
    for (int d = 0; d < 5; ++d) W[((size_t)hb * LL + l) * 5 + d] = w[d] * inv;
}

// ---------------------------------------------------------------------------
// Kernel C: Spart[hb][q][c] = sum_{l in q-th 128-chunk} V[hb][c][l] * U[hb][l]
// grid (H*B, 16), block 256
__global__ __launch_bounds__(256) void kC(const float* __restrict__ V,
                                          const float* __restrict__ U,
                                          float* __restrict__ Spart) {
    int hb = blockIdx.x;
    int q = blockIdx.y;
    int t = threadIdx.x;
    int c = t >> 2, sub = t & 3;
    const float* Vb = V + (size_t)(hb * 64 + c) * LL + q * 128;
    const float* Ub = U + (size_t)hb * LL + q * 128;
    float acc = 0.f;
    for (int l = sub; l < 128; l += 4) acc += Vb[l] * Ub[l];
    __shared__ float red[256];
    red[t] = acc;
    __syncthreads();
    if (sub == 0)
        Spart[((size_t)hb * 16 + q) * 64 + c] = red[t] + red[t + 1] + red[t + 2] + red[t + 3];
}

// ---------------------------------------------------------------------------
// Kernel D: val + residual -> x (registers); channel attention -> gate; write XG
// grid (B, L/64), block 256 (4 waves). lane = m, wave wv owns c-range wv*16+.. per head.
__global__ __launch_bounds__(256) void kD(const float* __restrict__ inp,
                                          const float* __restrict__ hidden,
                                          const float* __restrict__ V,
                                          const float* __restrict__ U,
                                          const float* __restrict__ W,
                                          const float* __restrict__ Spart,
                                          const float* __restrict__ w1T,
                                          const float* __restrict__ b1,
                                          const float* __restrict__ w2,
                                          const float* __restrict__ b2,
                                          float* __restrict__ XG) {
    int b = blockIdx.x;
    int m0 = blockIdx.y * 64;
    __shared__ float Vt[64][68];        // one head's V tile, halo 2 (17.4KB)
    __shared__ float dw_s[4][68][5];    // (w - u) per head/row (5.4KB)
    __shared__ float hid_s[64][64];     // 16KB
    __shared__ float S_s[256];          // 1KB
    __shared__ float partial[4][64][9]; // padded to 9 (9.2KB)
    int t = threadIdx.x;
    int m = t & 63;
    int wv = t >> 6;
    // --- phase 0 staging ---
    for (int i = 0; i < 16; ++i) {
        int r = wv * 16 + i;
        hid_s[r][m] = hidden[(size_t)(b * 64 + r) * LL + m0 + m];
    }
    for (int idx = t; idx < 4 * 68; idx += 256) {
        int h = idx / 68, j = idx % 68;
        int l = m0 - 2 + j;
        int hb = h * 8 + b;
        if (l >= 0 && l < LL) {
            float u = U[(size_t)hb * LL + l];
            const float* wp = &W[((size_t)hb * LL + l) * 5];
#pragma unroll
            for (int d = 0; d < 5; ++d) dw_s[h][j][d] = wp[d] - u;
        } else {
#pragma unroll
            for (int d = 0; d < 5; ++d) dw_s[h][j][d] = 0.f;
        }
    }
    {
        float s = 0.f;
        int hb = wv * 8 + b;
#pragma unroll
        for (int q = 0; q < 16; ++q) s += Spart[((size_t)hb * 16 + q) * 64 + m];
        S_s[wv * 64 + m] = s;
    }
    // --- phase 1: x = inputs + S + banded correction; x kept in registers ---
    float xr[4][16];
#pragma unroll
    for (int h = 0; h < 4; ++h) {
        __syncthreads();   // Vt reusable / staging done (h==0)
        int hb8 = h * 8 + b;
        for (int idx = t; idx < 64 * 68; idx += 256) {
            int c = idx / 68, j = idx % 68;
            int l = m0 - 2 + j;
            Vt[c][j] = (l >= 0 && l < LL) ? V[(size_t)(hb8 * 64 + c) * LL + l] : 0.f;
        }
        __syncthreads();   // Vt ready
        float dwv[5];
#pragma unroll
        for (int d = 0; d < 5; ++d) dwv[d] = dw_s[h][m + 4 - d][d];
#pragma unroll
        for (int cc = 0; cc < 16; ++cc) {
            int c = wv * 16 + cc;
            int ch = h * 64 + c;
            float v0 = Vt[c][m], v1 = Vt[c][m + 1], v2 = Vt[c][m + 2];
            float v3 = Vt[c][m + 3], v4 = Vt[c][m + 4];
            float val = S_s[ch] + v4 * dwv[0] + v3 * dwv[1] + v2 * dwv[2]
                      + v1 * dwv[3] + v0 * dwv[4];
            xr[h][cc] = inp[(size_t)(hb8 * 64 + c) * LL + m0 + m] + val;
        }
    }
    // --- phase 2: split-K channel attention, scalar weight loads ---
    float acc2[8] = {};
    int chbase = __builtin_amdgcn_readfirstlane(wv * 16);
#pragma unroll
    for (int h = 0; h < 4; ++h) {
#pragma unroll
        for (int cc = 0; cc < 16; ++cc) {
            const float* wp = w1T + (h * 64 + chbase + cc) * 8;
            float xv = xr[h][cc];
#pragma unroll
            for (int o = 0; o < 8; ++o) acc2[o] += wp[o] * xv;
        }
    }
#pragma unroll
    for (int i = 0; i < 16; ++i) {
        const float* wp = w1T + (256 + chbase + i) * 8;
        float xv = hid_s[chbase + i][m];
#pragma unroll
        for (int o = 0; o < 8; ++o) acc2[o] += wp[o] * xv;
    }
#pragma unroll
    for (int o = 0; o < 8; ++o) partial[wv][m][o] = acc2[o];
    __syncthreads();
    float a[8];
#pragma unroll
    for (int o = 0; o < 8; ++o) {
        float v = b1[o] + partial[0][m][o] + partial[1][m][o]
                + partial[2][m][o] + partial[3][m][o];
        a[o] = fmaxf(v, 0.f);
    }
    // --- phase 3: gate + write (each wave writes its own 64 channels) ---
#pragma unroll
    for (int h = 0; h < 4; ++h) {
#pragma unroll
        for (int cc = 0; cc < 16; ++cc) {
            int ch = h * 64 + chbase + cc;
            const float* wp = w2 + ch * 8;
            float g = b2[ch];
#pragma unroll
            for (int o = 0; o < 8; ++o) g += wp[o] * a[o];
            float gate = 1.f / (1.f + __expf(-g));
            XG[(size_t)(b * 256 + ch) * LL + m0 + m] = xr[h][cc] * gate;
        }
    }
}

// ---------------------------------------------------------------------------
// Kernel W: fold BN into conv weights, transpose layouts, build w1T.
__global__ __launch_bounds__(256) void kW(const float* __restrict__ pw1,
                                          const float* __restrict__ g1,
                                          const float* __restrict__ b1,
                                          const float* __restrict__ m1,
                                          const float* __restrict__ v1,
                                          const float* __restrict__ pw2,
                                          const float* __restrict__ g2,
                                          const float* __restrict__ b2,
                                          const float* __restrict__ m2,
                                          const float* __restrict__ v2,
                                          const float* __restrict__ w1,
                                          float* __restrict__ wE,
                                          float* __restrict__ biasE,
                                          float* __restrict__ wF,
                                          float* __restrict__ biasF,
                                          float* __restrict__ w1T) {
    int tid = blockIdx.x * 256 + threadIdx.x;
    int stride = gridDim.x * 256;
    for (int idx = tid; idx < 256 * 3 * 64; idx += stride) {
        int r = idx & 63;
        int tap = (idx >> 6) % 3;
        int ch = idx / 192;
        float inv = g1[r] * rsqrtf(v1[r] + EPS);
        wE[idx] = pw1[(r * 256 + ch) * 3 + tap] * inv;
    }
    for (int idx = tid; idx < 64 * 3 * 64; idx += stride) {
        int r = idx & 63;
        int tap = (idx >> 6) % 3;
        int c = idx / 192;
        float inv = g2[r] * rsqrtf(v2[r] + EPS);
        wF[idx] = pw2[(r * 64 + c) * 3 + tap] * inv;
    }
    for (int idx = tid; idx < 320 * 8; idx += stride)
        w1T[idx] = w1[(idx & 7) * 320 + (idx >> 3)];
    if (tid < 64) {
        float inv1 = g1[tid] * rsqrtf(v1[tid] + EPS);
        biasE[tid] = b1[tid] - m1[tid] * inv1;
        float inv2 = g2[tid] * rsqrtf(v2[tid] + EPS);
        biasF[tid] = b2[tid] - m2[tid] * inv2;
    }
}

// ---------------------------------------------------------------------------
// kConv<CIN>: conv3 (CIN -> 64) + folded BN + ReLU.
// grid (B, L/64), block 512 (8 waves). lane = m; wave wid owns r = wid*8..+8.
// Weights wave-uniform via readfirstlane -> scalar loads (s_load_dwordx8).
// LDS: xt[CIN][66] only (67.6KB for CIN=256 -> 2 blocks/CU).
template <int CIN>
__global__ __launch_bounds__(512) void kConv(const float* __restrict__ X,
                                             const float* __restrict__ wT,
                                             const float* __restrict__ bias,
                                             float* __restrict__ out) {
    int b = blockIdx.x;
    int m0 = blockIdx.y * 64;
    __shared__ float xt[CIN][66];
    int t = threadIdx.x;
    for (int idx = t; idx < CIN * 66; idx += 512) {
        int ch = idx / 66, j = idx % 66;
        int l = m0 - 1 + j;
        xt[ch][j] = (l >= 0 && l < LL) ? X[(size_t)(b * CIN + ch) * LL + l] : 0.f;
    }
    __syncthreads();
    int m = t & 63;
    int rb = __builtin_amdgcn_readfirstlane((t >> 6) * 8);
    const float* wb = wT + rb;          // wave-uniform base
    float acc[8] = {};
    for (int ch = 0; ch < CIN; ++ch) {
        float x0 = xt[ch][m];
        float x1 = xt[ch][m + 1];
        float x2 = xt[ch][m + 2];
        const float* wp = wb + ch * 192;   // [ch][tap][r]
#pragma unroll
        for (int i = 0; i < 8; ++i)
            acc[i] += wp[i] * x0 + wp[64 + i] * x1 + wp[128 + i] * x2;
    }
#pragma unroll
    for (int i = 0; i < 8; ++i) {
        int r = rb + i;
        out[(size_t)(b * 64 + r) * LL + m0 + m] = fmaxf(acc[i] + bias[r], 0.f);
    }
}

// ---------------------------------------------------------------------------
extern "C" void kernel_launch(void* const* d_in, const int* in_sizes, int n_in,
                              void* d_out, int out_size, void* d_ws, size_t ws_size,
                              hipStream_t stream) {
    (void)in_sizes; (void)n_in; (void)out_size; (void)ws_size;
    const float* inp    = (const float*)d_in[0];
    const float* hidden = (const float*)d_in[1];
    const float* key_w  = (const float*)d_in[2];
    const float* value_w= (const float*)d_in[3];
    const float* ca_w1  = (const float*)d_in[4];
    const float* ca_b1  = (const float*)d_in[5];
    const float* ca_w2  = (const float*)d_in[6];
    const float* ca_b2  = (const float*)d_in[7];
    const float* pw1    = (const float*)d_in[8];
    const float* bn1_g  = (const float*)d_in[9];
    const float* bn1_b  = (const float*)d_in[10];
    const float* bn1_m  = (const float*)d_in[11];
    const float* bn1_v  = (const float*)d_in[12];
    const float* pw2    = (const float*)d_in[13];
    const float* bn2_g  = (const float*)d_in[14];
    const float* bn2_b  = (const float*)d_in[15];
    const float* bn2_m  = (const float*)d_in[16];
    const float* bn2_v  = (const float*)d_in[17];

    float* ws = (float*)d_ws;
    const size_t KV = (size_t)HH * BB * CC * LL;    // 4,194,304 floats
    float* K = ws;
    float* V = ws + KV;
    float* U = ws + 2 * KV;                          // H*B*L = 65536
    float* W = U + (size_t)HH * BB * LL;             // H*B*L*5 = 327680
    float* Spart = W + (size_t)HH * BB * LL * 5;     // H*B*16*64 = 32768
    float* wE    = Spart + 32768;                    // 49152
    float* biasE = wE + 256 * 3 * 64;                // 64
    float* wF    = biasE + 64;                       // 12288
    float* biasF = wF + 64 * 3 * 64;                 // 64
    float* w1T   = biasF + 64;                       // 2560
    float* XG = K;   // alias: K dead after kB
    float* Y1 = V;   // alias: V dead after kConv<256> input? (V dead after kD/kC)

    kW<<<dim3(48), 256, 0, stream>>>(pw1, bn1_g, bn1_b, bn1_m, bn1_v,
                                     pw2, bn2_g, bn2_b, bn2_m, bn2_v,
                                     ca_w1, wE, biasE, wF, biasF, w1T);
    kA<<<dim3(HH * BB, LL / 64), 256, 0, stream>>>(inp, key_w, value_w, K, V);
    kB<<<dim3(HH * BB, LL / 128), 128, 0, stream>>>(K, hidden, U, W);
    kC<<<dim3(HH * BB, 16), 256, 0, stream>>>(V, U, Spart);
    kD<<<dim3(BB, LL / 64), 256, 0, stream>>>(inp, hidden, V, U, W, Spart,
                                              w1T, ca_b1, ca_w2, ca_b2, XG);
    kConv<256><<<dim3(BB, LL / 64), 512, 0, stream>>>(XG, wE, biasE, Y1);
    kConv<64><<<dim3(BB, LL / 64), 512, 0, stream>>>(Y1, wF, biasF, (float*)d_out);
}

// Round 5
// 147.158 us; speedup vs baseline: 3.1016x; 1.2801x over previous
//
#include <hip/hip_runtime.h>
#include <hip/hip_bf16.h>
#include <math.h>

// Sizes
#define HH 4
#define BB 8
#define CC 64
#define RR 64
#define LL 2048
#define AA 8
#define HC 256   // H*C
#define EPS 1e-5f

// ---------------------------------------------------------------------------
// Kernel A: fused K/V GEMM. Out rows 0..63 = K = key_w[h] @ inputs[h,b],
// rows 64..127 = V. grid (H*B, L/64) = (32,32), block 256 (4 waves).
__global__ __launch_bounds__(256) void kA(const float* __restrict__ inp,
                                          const float* __restrict__ kw,
                                          const float* __restrict__ vw,
                                          float* __restrict__ K,
                                          float* __restrict__ V) {
    int hb = blockIdx.x;
    int h = hb >> 3;
    int l0 = blockIdx.y * 64;
    __shared__ float in_s[64][64];
    __shared__ float wT[64][128];   // [c][row]; row<64: key, row>=64: value
    int t = threadIdx.x;
    const float* kwh = kw + h * 4096;
    const float* vwh = vw + h * 4096;
    for (int idx = t; idx < 4096; idx += 256) {
        int r = idx >> 6, c = idx & 63;
        wT[c][r] = kwh[idx];        // kwh[r*64+c]
        wT[c][64 + r] = vwh[idx];
    }
    for (int idx = t; idx < 4096; idx += 256) {
        int c = idx >> 6, j = idx & 63;
        in_s[c][j] = inp[(size_t)(hb * 64 + c) * LL + l0 + j];
    }
    __syncthreads();
    int w = t >> 6, lane = t & 63;
    int mg = lane & 15, rg = lane >> 4;
    int rowbase = w * 32 + rg * 8;
    int jx = mg * 4;
    float acc[8][4] = {};
    for (int c = 0; c < 64; ++c) {
        float4 x = *(const float4*)&in_s[c][jx];
        float4 wa = *(const float4*)&wT[c][rowbase];
        float4 wb = *(const float4*)&wT[c][rowbase + 4];
        float wv[8] = {wa.x, wa.y, wa.z, wa.w, wb.x, wb.y, wb.z, wb.w};
        float xv[4] = {x.x, x.y, x.z, x.w};
#pragma unroll
        for (int i = 0; i < 8; ++i)
#pragma unroll
            for (int k = 0; k < 4; ++k)
                acc[i][k] += wv[i] * xv[k];
    }
#pragma unroll
    for (int i = 0; i < 8; ++i) {
        int row = rowbase + i;
        float* dst = (row < 64 ? K : V);
        float4 o = {acc[i][0], acc[i][1], acc[i][2], acc[i][3]};
        *(float4*)&dst[(size_t)(hb * 64 + (row & 63)) * LL + l0 + jx] = o;
    }
}

// ---------------------------------------------------------------------------
// Kernel B: banded softmax stats per (h,b,l): u and w[5]
// grid (H*B, L/128), block 128
__global__ __launch_bounds__(128) void kB(const float* __restrict__ K,
                                          const float* __restrict__ hidden,
                                          float* __restrict__ U,
                                          float* __restrict__ W) {
    int hb = blockIdx.x;
    int b = hb & 7;
    int l0 = blockIdx.y * 128;
    __shared__ float k_s[64][132];
    __shared__ float h_s[64][128];
    const float* Kb = K + (size_t)(hb * 64) * LL;
    int t = threadIdx.x;
    for (int idx = t; idx < 64 * 132; idx += 128) {
        int r = idx / 132, j = idx % 132;
        int m = l0 - 2 + j;
        k_s[r][j] = (m >= 0 && m < LL) ? Kb[(size_t)r * LL + m] : 0.f;
    }
    const float* hbp = hidden + (size_t)(b * 64) * LL + l0;
    for (int r = 0; r < 64; ++r) h_s[r][t] = hbp[(size_t)r * LL + t];
    __syncthreads();
    int l = l0 + t;
    float raw[5];
    float mx = 0.f;
    int nv = 0;
#pragma unroll
    for (int d = 0; d < 5; ++d) {
        int m = l + d - 2;
        bool valid = (m >= 0 && m < LL);
        float acc = 0.f;
        if (valid) {
            for (int r = 0; r < 64; ++r) acc += h_s[r][t] * k_s[r][t + d];
            acc *= 0.125f;   // q scale 1/sqrt(64)
            nv++;
            mx = fmaxf(mx, acc);
        }
        raw[d] = valid ? acc : -1e30f;
    }
    float e0 = __expf(-mx);
    float Z = (float)(LL - nv) * e0;
    float w[5];
#pragma unroll
    for (int d = 0; d < 5; ++d) {
        float e = (raw[d] > -1e29f) ? __expf(raw[d] - mx) : 0.f;
        w[d] = e;
        Z += e;
    }
    float inv = 1.f / Z;
    U[(size_t)hb * LL + l] = e0 * inv;
#pragma unroll
    for (int d = 0; d < 5; ++d) W[((size_t)hb * LL + l) * 5 + d] = w[d] * inv;
}

// ---------------------------------------------------------------------------
// Kernel C: Spart[hb][q][c] = sum_{l in q-th 128-chunk} V[hb][c][l] * U[hb][l]
// grid (H*B, 16), block 256
__global__ __launch_bounds__(256) void kC(const float* __restrict__ V,
                                          const float* __restrict__ U,
                                          float* __restrict__ Spart) {
    int hb = blockIdx.x;
    int q = blockIdx.y;
    int t = threadIdx.x;
    int c = t >> 2, sub = t & 3;
    const float* Vb = V + (size_t)(hb * 64 + c) * LL + q * 128;
    const float* Ub = U + (size_t)hb * LL + q * 128;
    float acc = 0.f;
    for (int l = sub; l < 128; l += 4) acc += Vb[l] * Ub[l];
    __shared__ float red[256];
    red[t] = acc;
    __syncthreads();
    if (sub == 0)
        Spart[((size_t)hb * 16 + q) * 64 + c] = red[t] + red[t + 1] + red[t + 2] + red[t + 3];
}

// ---------------------------------------------------------------------------
// Kernel D: val + residual -> x (registers); channel attention -> gate; write XG
// grid (B, L/64), block 512 (8 waves). lane = m; wave wv owns c = wv*8..+8 per head.
__global__ __launch_bounds__(512) void kD(const float* __restrict__ inp,
                                          const float* __restrict__ hidden,
                                          const float* __restrict__ V,
                                          const float* __restrict__ U,
                                          const float* __restrict__ W,
                                          const float* __restrict__ Spart,
                                          const float* __restrict__ w1T,
                                          const float* __restrict__ b1,
                                          const float* __restrict__ w2,
                                          const float* __restrict__ b2,
                                          float* __restrict__ XG) {
    int b = blockIdx.x;
    int m0 = blockIdx.y * 64;
    __shared__ float Vt[64][68];        // one head's V tile, halo 2 (17.4KB)
    __shared__ float dw_s[4][68][5];    // (w - u) per head/row (5.4KB)
    __shared__ float S_s[256];          // 1KB
    __shared__ float partial[8][64][9]; // padded (18.4KB)
    int t = threadIdx.x;
    int m = t & 63;
    int wv = t >> 6;
    // --- phase 0 staging ---
    for (int idx = t; idx < 4 * 68; idx += 512) {
        int h = idx / 68, j = idx % 68;
        int l = m0 - 2 + j;
        int hb = h * 8 + b;
        if (l >= 0 && l < LL) {
            float u = U[(size_t)hb * LL + l];
            const float* wp = &W[((size_t)hb * LL + l) * 5];
#pragma unroll
            for (int d = 0; d < 5; ++d) dw_s[h][j][d] = wp[d] - u;
        } else {
#pragma unroll
            for (int d = 0; d < 5; ++d) dw_s[h][j][d] = 0.f;
        }
    }
    if (t < 256) {
        float s = 0.f;
        int hb = (t >> 6) * 8 + b;
#pragma unroll
        for (int q = 0; q < 16; ++q) s += Spart[((size_t)hb * 16 + q) * 64 + (t & 63)];
        S_s[t] = s;
    }
    // --- phase 1: x = inputs + S + banded correction; x kept in registers ---
    float xr[4][8];
#pragma unroll
    for (int h = 0; h < 4; ++h) {
        __syncthreads();   // Vt reusable / staging done (h==0)
        int hb8 = h * 8 + b;
        for (int idx = t; idx < 64 * 68; idx += 512) {
            int c = idx / 68, j = idx % 68;
            int l = m0 - 2 + j;
            Vt[c][j] = (l >= 0 && l < LL) ? V[(size_t)(hb8 * 64 + c) * LL + l] : 0.f;
        }
        __syncthreads();   // Vt ready
        float dwv[5];
#pragma unroll
        for (int d = 0; d < 5; ++d) dwv[d] = dw_s[h][m + 4 - d][d];
#pragma unroll
        for (int cc = 0; cc < 8; ++cc) {
            int c = wv * 8 + cc;
            int ch = h * 64 + c;
            float v0 = Vt[c][m], v1 = Vt[c][m + 1], v2 = Vt[c][m + 2];
            float v3 = Vt[c][m + 3], v4 = Vt[c][m + 4];
            float val = S_s[ch] + v4 * dwv[0] + v3 * dwv[1] + v2 * dwv[2]
                      + v1 * dwv[3] + v0 * dwv[4];
            xr[h][cc] = inp[(size_t)(hb8 * 64 + c) * LL + m0 + m] + val;
        }
    }
    // --- phase 2: split-K channel attention (own x channels + 8 hidden rows) ---
    float acc2[8] = {};
    int cb = __builtin_amdgcn_readfirstlane(wv * 8);
#pragma unroll
    for (int h = 0; h < 4; ++h) {
#pragma unroll
        for (int cc = 0; cc < 8; ++cc) {
            const float* wp = w1T + (h * 64 + cb + cc) * 8;
            float xv = xr[h][cc];
#pragma unroll
            for (int o = 0; o < 8; ++o) acc2[o] += wp[o] * xv;
        }
    }
#pragma unroll
    for (int i = 0; i < 8; ++i) {
        const float* wp = w1T + (256 + cb + i) * 8;
        float xv = hidden[(size_t)(b * 64 + cb + i) * LL + m0 + m];
#pragma unroll
        for (int o = 0; o < 8; ++o) acc2[o] += wp[o] * xv;
    }
#pragma unroll
    for (int o = 0; o < 8; ++o) partial[wv][m][o] = acc2[o];
    __syncthreads();
    float a[8];
#pragma unroll
    for (int o = 0; o < 8; ++o) {
        float v = b1[o];
#pragma unroll
        for (int p = 0; p < 8; ++p) v += partial[p][m][o];
        a[o] = fmaxf(v, 0.f);
    }
    // --- phase 3: gate + write (each wave writes its own 32 channels) ---
#pragma unroll
    for (int h = 0; h < 4; ++h) {
#pragma unroll
        for (int cc = 0; cc < 8; ++cc) {
            int ch = h * 64 + cb + cc;
            const float* wp = w2 + ch * 8;
            float g = b2[ch];
#pragma unroll
            for (int o = 0; o < 8; ++o) g += wp[o] * a[o];
            float gate = 1.f / (1.f + __expf(-g));
            XG[(size_t)(b * 256 + ch) * LL + m0 + m] = xr[h][cc] * gate;
        }
    }
}

// ---------------------------------------------------------------------------
// Kernel W: fold BN into conv weights; streaming layout [r>>2][ch][tap][r&3].
__global__ __launch_bounds__(256) void kW(const float* __restrict__ pw1,
                                          const float* __restrict__ g1,
                                          const float* __restrict__ b1,
                                          const float* __restrict__ m1,
                                          const float* __restrict__ v1,
                                          const float* __restrict__ pw2,
                                          const float* __restrict__ g2,
                                          const float* __restrict__ b2,
                                          const float* __restrict__ m2,
                                          const float* __restrict__ v2,
                                          const float* __restrict__ w1,
                                          float* __restrict__ wE,
                                          float* __restrict__ biasE,
                                          float* __restrict__ wF,
                                          float* __restrict__ biasF,
                                          float* __restrict__ w1T) {
    int tid = blockIdx.x * 256 + threadIdx.x;
    int stride = gridDim.x * 256;
    // pw1 flat idx = (r*256 + ch)*3 + tap
    for (int idx = tid; idx < 64 * 256 * 3; idx += stride) {
        int tap = idx % 3;
        int ch = (idx / 3) & 255;
        int r = idx / 768;
        float inv = g1[r] * rsqrtf(v1[r] + EPS);
        wE[(((r >> 2) * 256 + ch) * 3 + tap) * 4 + (r & 3)] = pw1[idx] * inv;
    }
    for (int idx = tid; idx < 64 * 64 * 3; idx += stride) {
        int tap = idx % 3;
        int ch = (idx / 3) & 63;
        int r = idx / 192;
        float inv = g2[r] * rsqrtf(v2[r] + EPS);
        wF[(((r >> 2) * 64 + ch) * 3 + tap) * 4 + (r & 3)] = pw2[idx] * inv;
    }
    for (int idx = tid; idx < 320 * 8; idx += stride)
        w1T[idx] = w1[(idx & 7) * 320 + (idx >> 3)];
    if (tid < 64) {
        float inv1 = g1[tid] * rsqrtf(v1[tid] + EPS);
        biasE[tid] = b1[tid] - m1[tid] * inv1;
        float inv2 = g2[tid] * rsqrtf(v2[tid] + EPS);
        biasF[tid] = b2[tid] - m2[tid] * inv2;
    }
}

// ---------------------------------------------------------------------------
// kConv<CIN>: conv3 (CIN -> 64) + folded BN + ReLU.
// grid (B, L/64), block 1024 (16 waves, 4/SIMD). lane = m; wave wid owns
// r = wid*4..+4. Weights wave-uniform scalar loads from the streaming layout
// [wid][ch][12]: 12 contiguous floats per ch -> s_load_dwordx8 + dwordx4,
// each wave reads its own contiguous CIN*48-byte run (full K$-line use).
template <int CIN>
__global__ __launch_bounds__(1024) void kConv(const float* __restrict__ X,
                                              const float* __restrict__ wT,
                                              const float* __restrict__ bias,
                                              float* __restrict__ out) {
    int b = blockIdx.x;
    int m0 = blockIdx.y * 64;
    __shared__ float xt[CIN][66];
    int t = threadIdx.x;
    for (int idx = t; idx < CIN * 66; idx += 1024) {
        int ch = idx / 66, j = idx % 66;
        int l = m0 - 1 + j;
        xt[ch][j] = (l >= 0 && l < LL) ? X[(size_t)(b * CIN + ch) * LL + l] : 0.f;
    }
    __syncthreads();
    int m = t & 63;
    int wid = __builtin_amdgcn_readfirstlane(t >> 6);   // 0..15
    const float* wbase = wT + (size_t)wid * (CIN * 12);
    float acc[4] = {};
#pragma unroll 4
    for (int ch = 0; ch < CIN; ++ch) {
        float x0 = xt[ch][m];
        float x1 = xt[ch][m + 1];
        float x2 = xt[ch][m + 2];
        const float* wp = wbase + ch * 12;
#pragma unroll
        for (int i = 0; i < 4; ++i)
            acc[i] += wp[i] * x0 + wp[4 + i] * x1 + wp[8 + i] * x2;
    }
#pragma unroll
    for (int i = 0; i < 4; ++i) {
        int r = wid * 4 + i;
        out[(size_t)(b * 64 + r) * LL + m0 + m] = fmaxf(acc[i] + bias[r], 0.f);
    }
}

// ---------------------------------------------------------------------------
extern "C" void kernel_launch(void* const* d_in, const int* in_sizes, int n_in,
                              void* d_out, int out_size, void* d_ws, size_t ws_size,
                              hipStream_t stream) {
    (void)in_sizes; (void)n_in; (void)out_size; (void)ws_size;
    const float* inp    = (const float*)d_in[0];
    const float* hidden = (const float*)d_in[1];
    const float* key_w  = (const float*)d_in[2];
    const float* value_w= (const float*)d_in[3];
    const float* ca_w1  = (const float*)d_in[4];
    const float* ca_b1  = (const float*)d_in[5];
    const float* ca_w2  = (const float*)d_in[6];
    const float* ca_b2  = (const float*)d_in[7];
    const float* pw1    = (const float*)d_in[8];
    const float* bn1_g  = (const float*)d_in[9];
    const float* bn1_b  = (const float*)d_in[10];
    const float* bn1_m  = (const float*)d_in[11];
    const float* bn1_v  = (const float*)d_in[12];
    const float* pw2    = (const float*)d_in[13];
    const float* bn2_g  = (const float*)d_in[14];
    const float* bn2_b  = (const float*)d_in[15];
    const float* bn2_m  = (const float*)d_in[16];
    const float* bn2_v  = (const float*)d_in[17];

    float* ws = (float*)d_ws;
    const size_t KV = (size_t)HH * BB * CC * LL;    // 4,194,304 floats
    float* K = ws;
    float* V = ws + KV;
    float* U = ws + 2 * KV;                          // H*B*L = 65536
    float* W = U + (size_t)HH * BB * LL;             // H*B*L*5 = 327680
    float* Spart = W + (size_t)HH * BB * LL * 5;     // H*B*16*64 = 32768
    float* wE    = Spart + 32768;                    // 49152
    float* biasE = wE + 256 * 3 * 64;                // 64
    float* wF    = biasE + 64;                       // 12288
    float* biasF = wF + 64 * 3 * 64;                 // 64
    float* w1T   = biasF + 64;                       // 2560
    float* XG = K;   // alias: K dead after kB
    float* Y1 = V;   // alias: V dead after kD/kC

    kW<<<dim3(48), 256, 0, stream>>>(pw1, bn1_g, bn1_b, bn1_m, bn1_v,
                                     pw2, bn2_g, bn2_b, bn2_m, bn2_v,
                                     ca_w1, wE, biasE, wF, biasF, w1T);
    kA<<<dim3(HH * BB, LL / 64), 256, 0, stream>>>(inp, key_w, value_w, K, V);
    kB<<<dim3(HH * BB, LL / 128), 128, 0, stream>>>(K, hidden, U, W);
    kC<<<dim3(HH * BB, 16), 256, 0, stream>>>(V, U, Spart);
    kD<<<dim3(BB, LL / 64), 512, 0, stream>>>(inp, hidden, V, U, W, Spart,
                                              w1T, ca_b1, ca_w2, ca_b2, XG);
    kConv<256><<<dim3(BB, LL / 64), 1024, 0, stream>>>(XG, wE, biasE, Y1);
    kConv<64><<<dim3(BB, LL / 64), 1024, 0, stream>>>(Y1, wF, biasF, (float*)d_out);
}

// Round 6
// 141.037 us; speedup vs baseline: 3.2362x; 1.0434x over previous
//
#include <hip/hip_runtime.h>
#include <hip/hip_bf16.h>
#include <math.h>

// Sizes
#define HH 4
#define BB 8
#define CC 64
#define RR 64
#define LL 2048
#define AA 8
#define HC 256   // H*C
#define EPS 1e-5f
#define CHP 266  // LDS row pad: 133 dwords/row, gcd(133,32)=1 -> conflict-free

typedef unsigned short ushort_t;
typedef __attribute__((ext_vector_type(8))) short short8;
typedef __attribute__((ext_vector_type(4))) float f32x4;

static __device__ __forceinline__ ushort_t f2bf(float x) {
    unsigned u = __float_as_uint(x);
    unsigned r = (u + 0x7FFF + ((u >> 16) & 1)) >> 16;
    return (ushort_t)r;
}
static __device__ __forceinline__ float bf2f(ushort_t h) {
    return __uint_as_float(((unsigned)h) << 16);
}

// ---------------------------------------------------------------------------
// Kernel A: fused K/V GEMM. Out rows 0..63 = K = key_w[h] @ inputs[h,b],
// rows 64..127 = V. grid (H*B, L/64) = (32,32), block 256 (4 waves).
__global__ __launch_bounds__(256) void kA(const float* __restrict__ inp,
                                          const float* __restrict__ kw,
                                          const float* __restrict__ vw,
                                          float* __restrict__ K,
                                          float* __restrict__ V) {
    int hb = blockIdx.x;
    int h = hb >> 3;
    int l0 = blockIdx.y * 64;
    __shared__ float in_s[64][64];
    __shared__ float wT[64][128];   // [c][row]; row<64: key, row>=64: value
    int t = threadIdx.x;
    const float* kwh = kw + h * 4096;
    const float* vwh = vw + h * 4096;
    for (int idx = t; idx < 4096; idx += 256) {
        int r = idx >> 6, c = idx & 63;
        wT[c][r] = kwh[idx];        // kwh[r*64+c]
        wT[c][64 + r] = vwh[idx];
    }
    for (int idx = t; idx < 4096; idx += 256) {
        int c = idx >> 6, j = idx & 63;
        in_s[c][j] = inp[(size_t)(hb * 64 + c) * LL + l0 + j];
    }
    __syncthreads();
    int w = t >> 6, lane = t & 63;
    int mg = lane & 15, rg = lane >> 4;
    int rowbase = w * 32 + rg * 8;
    int jx = mg * 4;
    float acc[8][4] = {};
    for (int c = 0; c < 64; ++c) {
        float4 x = *(const float4*)&in_s[c][jx];
        float4 wa = *(const float4*)&wT[c][rowbase];
        float4 wb = *(const float4*)&wT[c][rowbase + 4];
        float wv[8] = {wa.x, wa.y, wa.z, wa.w, wb.x, wb.y, wb.z, wb.w};
        float xv[4] = {x.x, x.y, x.z, x.w};
#pragma unroll
        for (int i = 0; i < 8; ++i)
#pragma unroll
            for (int k = 0; k < 4; ++k)
                acc[i][k] += wv[i] * xv[k];
    }
#pragma unroll
    for (int i = 0; i < 8; ++i) {
        int row = rowbase + i;
        float* dst = (row < 64 ? K : V);
        float4 o = {acc[i][0], acc[i][1], acc[i][2], acc[i][3]};
        *(float4*)&dst[(size_t)(hb * 64 + (row & 63)) * LL + l0 + jx] = o;
    }
}

// ---------------------------------------------------------------------------
// Kernel B: banded softmax stats per (h,b,l): u and w[5]
// grid (H*B, L/128), block 128
__global__ __launch_bounds__(128) void kB(const float* __restrict__ K,
                                          const float* __restrict__ hidden,
                                          float* __restrict__ U,
                                          float* __restrict__ W) {
    int hb = blockIdx.x;
    int b = hb & 7;
    int l0 = blockIdx.y * 128;
    __shared__ float k_s[64][132];
    __shared__ float h_s[64][128];
    const float* Kb = K + (size_t)(hb * 64) * LL;
    int t = threadIdx.x;
    for (int idx = t; idx < 64 * 132; idx += 128) {
        int r = idx / 132, j = idx % 132;
        int m = l0 - 2 + j;
        k_s[r][j] = (m >= 0 && m < LL) ? Kb[(size_t)r * LL + m] : 0.f;
    }
    const float* hbp = hidden + (size_t)(b * 64) * LL + l0;
    for (int r = 0; r < 64; ++r) h_s[r][t] = hbp[(size_t)r * LL + t];
    __syncthreads();
    int l = l0 + t;
    float raw[5];
    float mx = 0.f;
    int nv = 0;
#pragma unroll
    for (int d = 0; d < 5; ++d) {
        int m = l + d - 2;
        bool valid = (m >= 0 && m < LL);
        float acc = 0.f;
        if (valid) {
            for (int r = 0; r < 64; ++r) acc += h_s[r][t] * k_s[r][t + d];
            acc *= 0.125f;   // q scale 1/sqrt(64)
            nv++;
            mx = fmaxf(mx, acc);
        }
        raw[d] = valid ? acc : -1e30f;
    }
    float e0 = __expf(-mx);
    float Z = (float)(LL - nv) * e0;
    float w[5];
#pragma unroll
    for (int d = 0; d < 5; ++d) {
        float e = (raw[d] > -1e29f) ? __expf(raw[d] - mx) : 0.f;
        w[d] = e;
        Z += e;
    }
    float inv = 1.f / Z;
    U[(size_t)hb * LL + l] = e0 * inv;
#pragma unroll
    for (int d = 0; d < 5; ++d) W[((size_t)hb * LL + l) * 5 + d] = w[d] * inv;
}

// ---------------------------------------------------------------------------
// Kernel C: Spart[hb][q][c] = sum_{l in q-th 128-chunk} V[hb][c][l] * U[hb][l]
// grid (H*B, 16), block 256
__global__ __launch_bounds__(256) void kC(const float* __restrict__ V,
                                          const float* __restrict__ U,
                                          float* __restrict__ Spart) {
    int hb = blockIdx.x;
    int q = blockIdx.y;
    int t = threadIdx.x;
    int c = t >> 2, sub = t & 3;
    const float* Vb = V + (size_t)(hb * 64 + c) * LL + q * 128;
    const float* Ub = U + (size_t)hb * LL + q * 128;
    float acc = 0.f;
    for (int l = sub; l < 128; l += 4) acc += Vb[l] * Ub[l];
    __shared__ float red[256];
    red[t] = acc;
    __syncthreads();
    if (sub == 0)
        Spart[((size_t)hb * 16 + q) * 64 + c] = red[t] + red[t + 1] + red[t + 2] + red[t + 3];
}

// ---------------------------------------------------------------------------
// Kernel D: val + residual -> x (registers); channel attention -> gate; write XG
// grid (B, L/64), block 512 (8 waves). lane = m; wave wv owns c = wv*8..+8 per head.
__global__ __launch_bounds__(512) void kD(const float* __restrict__ inp,
                                          const float* __restrict__ hidden,
                                          const float* __restrict__ V,
                                          const float* __restrict__ U,
                                          const float* __restrict__ W,
                                          const float* __restrict__ Spart,
                                          const float* __restrict__ w1T,
                                          const float* __restrict__ b1,
                                          const float* __restrict__ w2,
                                          const float* __restrict__ b2,
                                          float* __restrict__ XG) {
    int b = blockIdx.x;
    int m0 = blockIdx.y * 64;
    __shared__ float Vt[64][68];        // one head's V tile, halo 2 (17.4KB)
    __shared__ float dw_s[4][68][5];    // (w - u) per head/row (5.4KB)
    __shared__ float S_s[256];          // 1KB
    __shared__ float partial[8][64][9]; // padded (18.4KB)
    int t = threadIdx.x;
    int m = t & 63;
    int wv = t >> 6;
    // --- phase 0 staging ---
    for (int idx = t; idx < 4 * 68; idx += 512) {
        int h = idx / 68, j = idx % 68;
        int l = m0 - 2 + j;
        int hb = h * 8 + b;
        if (l >= 0 && l < LL) {
            float u = U[(size_t)hb * LL + l];
            const float* wp = &W[((size_t)hb * LL + l) * 5];
#pragma unroll
            for (int d = 0; d < 5; ++d) dw_s[h][j][d] = wp[d] - u;
        } else {
#pragma unroll
            for (int d = 0; d < 5; ++d) dw_s[h][j][d] = 0.f;
        }
    }
    if (t < 256) {
        float s = 0.f;
        int hb = (t >> 6) * 8 + b;
#pragma unroll
        for (int q = 0; q < 16; ++q) s += Spart[((size_t)hb * 16 + q) * 64 + (t & 63)];
        S_s[t] = s;
    }
    // --- phase 1: x = inputs + S + banded correction; x kept in registers ---
    float xr[4][8];
#pragma unroll
    for (int h = 0; h < 4; ++h) {
        __syncthreads();   // Vt reusable / staging done (h==0)
        int hb8 = h * 8 + b;
        for (int idx = t; idx < 64 * 68; idx += 512) {
            int c = idx / 68, j = idx % 68;
            int l = m0 - 2 + j;
            Vt[c][j] = (l >= 0 && l < LL) ? V[(size_t)(hb8 * 64 + c) * LL + l] : 0.f;
        }
        __syncthreads();   // Vt ready
        float dwv[5];
#pragma unroll
        for (int d = 0; d < 5; ++d) dwv[d] = dw_s[h][m + 4 - d][d];
#pragma unroll
        for (int cc = 0; cc < 8; ++cc) {
            int c = wv * 8 + cc;
            int ch = h * 64 + c;
            float v0 = Vt[c][m], v1 = Vt[c][m + 1], v2 = Vt[c][m + 2];
            float v3 = Vt[c][m + 3], v4 = Vt[c][m + 4];
            float val = S_s[ch] + v4 * dwv[0] + v3 * dwv[1] + v2 * dwv[2]
                      + v1 * dwv[3] + v0 * dwv[4];
            xr[h][cc] = inp[(size_t)(hb8 * 64 + c) * LL + m0 + m] + val;
        }
    }
    // --- phase 2: split-K channel attention (own x channels + 8 hidden rows) ---
    float acc2[8] = {};
    int cb = __builtin_amdgcn_readfirstlane(wv * 8);
#pragma unroll
    for (int h = 0; h < 4; ++h) {
#pragma unroll
        for (int cc = 0; cc < 8; ++cc) {
            const float* wp = w1T + (h * 64 + cb + cc) * 8;
            float xv = xr[h][cc];
#pragma unroll
            for (int o = 0; o < 8; ++o) acc2[o] += wp[o] * xv;
        }
    }
#pragma unroll
    for (int i = 0; i < 8; ++i) {
        const float* wp = w1T + (256 + cb + i) * 8;
        float xv = hidden[(size_t)(b * 64 + cb + i) * LL + m0 + m];
#pragma unroll
        for (int o = 0; o < 8; ++o) acc2[o] += wp[o] * xv;
    }
#pragma unroll
    for (int o = 0; o < 8; ++o) partial[wv][m][o] = acc2[o];
    __syncthreads();
    float a[8];
#pragma unroll
    for (int o = 0; o < 8; ++o) {
        float v = b1[o];
#pragma unroll
        for (int p = 0; p < 8; ++p) v += partial[p][m][o];
        a[o] = fmaxf(v, 0.f);
    }
    // --- phase 3: gate + write (each wave writes its own 32 channels) ---
#pragma unroll
    for (int h = 0; h < 4; ++h) {
#pragma unroll
        for (int cc = 0; cc < 8; ++cc) {
            int ch = h * 64 + cb + cc;
            const float* wp = w2 + ch * 8;
            float g = b2[ch];
#pragma unroll
            for (int o = 0; o < 8; ++o) g += wp[o] * a[o];
            float gate = 1.f / (1.f + __expf(-g));
            XG[(size_t)(b * 256 + ch) * LL + m0 + m] = xr[h][cc] * gate;
        }
    }
}

// ---------------------------------------------------------------------------
// Kernel W: fold BN into conv weights.
// wEb: bf16 A-fragment layout for kConvM (mfma 16x16x32), k = tap*256 + ch:
//   flat = ((rg*24 + ks)*64 + lane)*8 + j, rg=r>>4, r = rg*16 + (lane&15),
//   k = ks*32 + (lane>>4)*8 + j.
// wF: fp32 streaming layout [r>>2][ch][tap][r&3] for kConv<64>.
__global__ __launch_bounds__(256) void kW(const float* __restrict__ pw1,
                                          const float* __restrict__ g1,
                                          const float* __restrict__ b1,
                                          const float* __restrict__ m1,
                                          const float* __restrict__ v1,
                                          const float* __restrict__ pw2,
                                          const float* __restrict__ g2,
                                          const float* __restrict__ b2,
                                          const float* __restrict__ m2,
                                          const float* __restrict__ v2,
                                          const float* __restrict__ w1,
                                          ushort_t* __restrict__ wEb,
                                          float* __restrict__ biasE,
                                          float* __restrict__ wF,
                                          float* __restrict__ biasF,
                                          float* __restrict__ w1T) {
    int tid = blockIdx.x * 256 + threadIdx.x;
    int stride = gridDim.x * 256;
    // A-fragment bf16 pack for conv1 MFMA
    for (int idx = tid; idx < 4 * 24 * 64 * 8; idx += stride) {
        int j = idx & 7;
        int lane = (idx >> 3) & 63;
        int t2 = idx >> 9;
        int ks = t2 % 24;
        int rg = t2 / 24;              // 0..3
        int r = rg * 16 + (lane & 15);
        int k = ks * 32 + (lane >> 4) * 8 + j;
        int tap = k >> 8;              // k / 256
        int ch = k & 255;              // k % 256
        float inv = g1[r] * rsqrtf(v1[r] + EPS);
        wEb[idx] = f2bf(pw1[(r * 256 + ch) * 3 + tap] * inv);
    }
    for (int idx = tid; idx < 64 * 64 * 3; idx += stride) {
        int tap = idx % 3;
        int ch = (idx / 3) & 63;
        int r = idx / 192;
        float inv = g2[r] * rsqrtf(v2[r] + EPS);
        wF[(((r >> 2) * 64 + ch) * 3 + tap) * 4 + (r & 3)] = pw2[idx] * inv;
    }
    for (int idx = tid; idx < 320 * 8; idx += stride)
        w1T[idx] = w1[(idx & 7) * 320 + (idx >> 3)];
    if (tid < 64) {
        float inv1 = g1[tid] * rsqrtf(v1[tid] + EPS);
        biasE[tid] = b1[tid] - m1[tid] * inv1;
        float inv2 = g2[tid] * rsqrtf(v2[tid] + EPS);
        biasF[tid] = b2[tid] - m2[tid] * inv2;
    }
}

// ---------------------------------------------------------------------------
// kConvM: conv1 (256 -> 64) + folded BN + ReLU via bf16 MFMA, split-x 2-pass.
// grid (B, L/64), block 256 (4 waves). Wave wid: wm = wid&1 (r-half),
// wn = wid>>1 (m-half). Each wave: 32x32 output via 2x2 mfma_16x16x32 tiles,
// K = 768 (tap-major), 24 K-steps, acc += A*(Bhi) + A*(Blo).
__global__ __launch_bounds__(256) void kConvM(const float* __restrict__ XG,
                                              const ushort_t* __restrict__ wEb,
                                              const float* __restrict__ biasE,
                                              float* __restrict__ Y1) {
    int b = blockIdx.x;
    int l0 = blockIdx.y * 64;
    __shared__ ushort_t xts[2][66][CHP];   // [hi/lo][row=l-l0+1][ch], 70.2KB
    __shared__ float bias_s[64];
    int t = threadIdx.x;
    if (t < 64) bias_s[t] = biasE[t];
    // stage + bf16 split: 256 ch x 66 rows; consecutive t -> consecutive l (coalesced)
    for (int base = 0; base < 66 * 256; base += 256) {
        int idx = base + t;
        int ch = idx / 66, row = idx % 66;
        int l = l0 - 1 + row;
        float x = (l >= 0 && l < LL) ? XG[(size_t)(b * 256 + ch) * LL + l] : 0.f;
        ushort_t hi = f2bf(x);
        ushort_t lo = f2bf(x - bf2f(hi));
        xts[0][row][ch] = hi;
        xts[1][row][ch] = lo;
    }
    __syncthreads();
    int lane = t & 63;
    int wid = t >> 6;
    int wm = wid & 1, wn = wid >> 1;
    int a = lane & 15;       // row (A) / col (B,C) within 16-tile
    int kg = lane >> 4;      // k-group 0..3
    f32x4 acc[2][2] = {};
    union U8 { unsigned u[4]; short8 s; };
#pragma unroll 4
    for (int ks = 0; ks < 24; ++ks) {
        int tap = ks >> 3;
        int ch0 = ((ks & 7) << 5) + (kg << 3);   // (ks%8)*32 + kg*8
        short8 afr[2];
#pragma unroll
        for (int tr = 0; tr < 2; ++tr) {
            const ushort_t* ap = wEb + ((((size_t)(wm * 2 + tr) * 24 + ks) * 64 + lane) << 3);
            afr[tr] = *(const short8*)ap;
        }
#pragma unroll
        for (int tc = 0; tc < 2; ++tc) {
            int row = wn * 32 + tc * 16 + a + tap;   // x row = m + tap (halo +1 folded)
            const ushort_t* xh = &xts[0][row][ch0];
            const ushort_t* xl = &xts[1][row][ch0];
            U8 bh, bl;
#pragma unroll
            for (int q = 0; q < 4; ++q) {
                bh.u[q] = *(const unsigned*)(xh + 2 * q);
                bl.u[q] = *(const unsigned*)(xl + 2 * q);
            }
#pragma unroll
            for (int tr = 0; tr < 2; ++tr) {
                acc[tr][tc] = __builtin_amdgcn_mfma_f32_16x16x32_bf16(
                    afr[tr], bh.s, acc[tr][tc], 0, 0, 0);
                acc[tr][tc] = __builtin_amdgcn_mfma_f32_16x16x32_bf16(
                    afr[tr], bl.s, acc[tr][tc], 0, 0, 0);
            }
        }
    }
    // epilogue: C/D layout col=lane&15, row=(lane>>4)*4+reg (m89-verified)
#pragma unroll
    for (int tr = 0; tr < 2; ++tr) {
#pragma unroll
        for (int tc = 0; tc < 2; ++tc) {
            int m = wn * 32 + tc * 16 + a;
#pragma unroll
            for (int reg = 0; reg < 4; ++reg) {
                int r = wm * 32 + tr * 16 + kg * 4 + reg;
                float y = acc[tr][tc][reg] + bias_s[r];
                Y1[(size_t)(b * 64 + r) * LL + l0 + m] = fmaxf(y, 0.f);
            }
        }
    }
}

// ---------------------------------------------------------------------------
// kConv<CIN>: conv3 (CIN -> 64) + folded BN + ReLU (fp32, scalar weights).
// Used for conv2 (CIN=64). grid (B, L/64), block 1024.
template <int CIN>
__global__ __launch_bounds__(1024) void kConv(const float* __restrict__ X,
                                              const float* __restrict__ wT,
                                              const float* __restrict__ bias,
                                              float* __restrict__ out) {
    int b = blockIdx.x;
    int m0 = blockIdx.y * 64;
    __shared__ float xt[CIN][66];
    int t = threadIdx.x;
    for (int idx = t; idx < CIN * 66; idx += 1024) {
        int ch = idx / 66, j = idx % 66;
        int l = m0 - 1 + j;
        xt[ch][j] = (l >= 0 && l < LL) ? X[(size_t)(b * CIN + ch) * LL + l] : 0.f;
    }
    __syncthreads();
    int m = t & 63;
    int wid = __builtin_amdgcn_readfirstlane(t >> 6);   // 0..15
    const float* wbase = wT + (size_t)wid * (CIN * 12);
    float acc[4] = {};
#pragma unroll 4
    for (int ch = 0; ch < CIN; ++ch) {
        float x0 = xt[ch][m];
        float x1 = xt[ch][m + 1];
        float x2 = xt[ch][m + 2];
        const float* wp = wbase + ch * 12;
#pragma unroll
        for (int i = 0; i < 4; ++i)
            acc[i] += wp[i] * x0 + wp[4 + i] * x1 + wp[8 + i] * x2;
    }
#pragma unroll
    for (int i = 0; i < 4; ++i) {
        int r = wid * 4 + i;
        out[(size_t)(b * 64 + r) * LL + m0 + m] = fmaxf(acc[i] + bias[r], 0.f);
    }
}

// ---------------------------------------------------------------------------
extern "C" void kernel_launch(void* const* d_in, const int* in_sizes, int n_in,
                              void* d_out, int out_size, void* d_ws, size_t ws_size,
                              hipStream_t stream) {
    (void)in_sizes; (void)n_in; (void)out_size; (void)ws_size;
    const float* inp    = (const float*)d_in[0];
    const float* hidden = (const float*)d_in[1];
    const float* key_w  = (const float*)d_in[2];
    const float* value_w= (const float*)d_in[3];
    const float* ca_w1  = (const float*)d_in[4];
    const float* ca_b1  = (const float*)d_in[5];
    const float* ca_w2  = (const float*)d_in[6];
    const float* ca_b2  = (const float*)d_in[7];
    const float* pw1    = (const float*)d_in[8];
    const float* bn1_g  = (const float*)d_in[9];
    const float* bn1_b  = (const float*)d_in[10];
    const float* bn1_m  = (const float*)d_in[11];
    const float* bn1_v  = (const float*)d_in[12];
    const float* pw2    = (const float*)d_in[13];
    const float* bn2_g  = (const float*)d_in[14];
    const float* bn2_b  = (const float*)d_in[15];
    const float* bn2_m  = (const float*)d_in[16];
    const float* bn2_v  = (const float*)d_in[17];

    float* ws = (float*)d_ws;
    const size_t KV = (size_t)HH * BB * CC * LL;    // 4,194,304 floats
    float* K = ws;
    float* V = ws + KV;
    float* U = ws + 2 * KV;                          // H*B*L = 65536
    float* W = U + (size_t)HH * BB * LL;             // H*B*L*5 = 327680
    float* Spart = W + (size_t)HH * BB * LL * 5;     // H*B*16*64 = 32768
    float* wF    = Spart + 32768;                    // 12288
    float* biasF = wF + 64 * 3 * 64;                 // 64
    float* biasE = biasF + 64;                       // 64
    float* w1T   = biasE + 64;                       // 2560
    ushort_t* wEb = (ushort_t*)(w1T + 2560);         // 49152 bf16 (16B-aligned)
    float* XG = K;   // alias: K dead after kB
    float* Y1 = V;   // alias: V dead after kD/kC

    kW<<<dim3(48), 256, 0, stream>>>(pw1, bn1_g, bn1_b, bn1_m, bn1_v,
                                     pw2, bn2_g, bn2_b, bn2_m, bn2_v,
                                     ca_w1, wEb, biasE, wF, biasF, w1T);
    kA<<<dim3(HH * BB, LL / 64), 256, 0, stream>>>(inp, key_w, value_w, K, V);
    kB<<<dim3(HH * BB, LL / 128), 128, 0, stream>>>(K, hidden, U, W);
    kC<<<dim3(HH * BB, 16), 256, 0, stream>>>(V, U, Spart);
    kD<<<dim3(BB, LL / 64), 512, 0, stream>>>(inp, hidden, V, U, W, Spart,
                                              w1T, ca_b1, ca_w2, ca_b2, XG);
    kConvM<<<dim3(BB, LL / 64), 256, 0, stream>>>(XG, wEb, biasE, Y1);
    kConv<64><<<dim3(BB, LL / 64), 1024, 0, stream>>>(Y1, wF, biasF, (float*)d_out);
}